// Round 4
// baseline (472.739 us; speedup 1.0000x reference)
//
#include <hip/hip_runtime.h>

// bf16 MFMA fragment types (gfx950: __builtin_amdgcn_mfma_f32_16x16x32_bf16 takes v8bf16)
typedef __attribute__((ext_vector_type(8))) __bf16 bfrag;
typedef __attribute__((ext_vector_type(4))) float f32x4;

#define MFMA(a, b, c) __builtin_amdgcn_mfma_f32_16x16x32_bf16((a), (b), (c), 0, 0, 0)

#define D_MODEL 1024
#define SEQ     2048
#define NB      2
#define NH      16
#define HD      64
#define MROWS   (NB * SEQ)   // 4096

// ---------------------------------------------------------------------------
// GEMM: Y[M=4096][N=1024] = A[M][K=1024] * W[K=1024][N] + bias
// Inputs fp32 (A for MODE 0, W, bias); internal compute bf16 MFMA.
// W is natural row-major [K][N]; transposed to [n][k] bf16 during LDS staging.
// 128x128 block tile, BK=64, 4 waves each 64x64 via 4x4 of 16x16x32 MFMA.
// MODE 0: A = fp32 x;      dst = bf16 QKV scatter [z][b,h,s,d]
// MODE 1: A = bf16 attn_o; dst = fp32 row-major [m][n]
// ---------------------------------------------------------------------------
template <int MODE>
__global__ __launch_bounds__(256) void k_gemm128(
    const void* __restrict__ Ap,
    const float* __restrict__ W0, const float* __restrict__ W1,
    const float* __restrict__ W2,
    const float* __restrict__ b0, const float* __restrict__ b1,
    const float* __restrict__ b2, void* __restrict__ dstp)
{
    // stride 72 elem = 144 B (multiple of 16 -> aligned b128 reads)
    alignas(16) __shared__ __bf16 As[128 * 72];
    alignas(16) __shared__ __bf16 Bs[128 * 72];   // [n][k] after staging transpose

    const int tid = threadIdx.x;
    const int z = blockIdx.z;
    const int m0 = blockIdx.y * 128;
    const int n0 = blockIdx.x * 128;
    const float* W    = (z == 0) ? W0 : (z == 1) ? W1 : W2;
    const float* bias = (z == 0) ? b0 : (z == 1) ? b1 : b2;

    const int wid = tid >> 6, lane = tid & 63;
    const int quad = lane >> 4, l16 = lane & 15;
    const int wRow = (wid >> 1) * 64, wCol = (wid & 1) * 64;

    f32x4 acc[4][4];
    const f32x4 zero = {0.f, 0.f, 0.f, 0.f};
    for (int mi = 0; mi < 4; ++mi)
        for (int ni = 0; ni < 4; ++ni) acc[mi][ni] = zero;

    const int srow = tid >> 3;          // 0..31 (A staging)
    const int sseg = (tid & 7) * 8;     // 0..56
    const int bkrow = tid >> 4;         // 0..15 (W staging)
    const int bnseg = (tid & 15) * 8;   // 0..120

    for (int k0 = 0; k0 < D_MODEL; k0 += 64) {
        // ---- A tile -> As[m][k] (bf16) ----
        if (MODE == 0) {
            const float* A = (const float*)Ap;
            for (int it = 0; it < 4; ++it) {
                int row = srow + it * 32;
                const float* src = &A[(size_t)(m0 + row) * D_MODEL + k0 + sseg];
                float4 f0 = *(const float4*)src;
                float4 f1 = *(const float4*)(src + 4);
                union { uint4 u; __bf16 hx[8]; } cv;
                cv.hx[0] = (__bf16)f0.x; cv.hx[1] = (__bf16)f0.y;
                cv.hx[2] = (__bf16)f0.z; cv.hx[3] = (__bf16)f0.w;
                cv.hx[4] = (__bf16)f1.x; cv.hx[5] = (__bf16)f1.y;
                cv.hx[6] = (__bf16)f1.z; cv.hx[7] = (__bf16)f1.w;
                *(uint4*)&As[row * 72 + sseg] = cv.u;
            }
        } else {
            const __bf16* A = (const __bf16*)Ap;
            for (int it = 0; it < 4; ++it) {
                int row = srow + it * 32;
                uint4 va = *(const uint4*)&A[(size_t)(m0 + row) * D_MODEL + k0 + sseg];
                *(uint4*)&As[row * 72 + sseg] = va;
            }
        }
        // ---- W tile: global fp32 [k][n] -> LDS bf16 [n][k] (scalar scatter) ----
        for (int it = 0; it < 4; ++it) {
            int krow = bkrow + it * 16;
            const float* src = &W[(size_t)(k0 + krow) * D_MODEL + n0 + bnseg];
            float4 f0 = *(const float4*)src;
            float4 f1 = *(const float4*)(src + 4);
            Bs[(bnseg + 0) * 72 + krow] = (__bf16)f0.x;
            Bs[(bnseg + 1) * 72 + krow] = (__bf16)f0.y;
            Bs[(bnseg + 2) * 72 + krow] = (__bf16)f0.z;
            Bs[(bnseg + 3) * 72 + krow] = (__bf16)f0.w;
            Bs[(bnseg + 4) * 72 + krow] = (__bf16)f1.x;
            Bs[(bnseg + 5) * 72 + krow] = (__bf16)f1.y;
            Bs[(bnseg + 6) * 72 + krow] = (__bf16)f1.z;
            Bs[(bnseg + 7) * 72 + krow] = (__bf16)f1.w;
        }
        __syncthreads();
        for (int kk = 0; kk < 64; kk += 32) {
            bfrag af[4], bf[4];
            for (int mi = 0; mi < 4; ++mi)
                af[mi] = *(const bfrag*)&As[(wRow + mi * 16 + l16) * 72 + kk + quad * 8];
            for (int ni = 0; ni < 4; ++ni)
                bf[ni] = *(const bfrag*)&Bs[(wCol + ni * 16 + l16) * 72 + kk + quad * 8];
            for (int mi = 0; mi < 4; ++mi)
                for (int ni = 0; ni < 4; ++ni)
                    acc[mi][ni] = MFMA(af[mi], bf[ni], acc[mi][ni]);
        }
        __syncthreads();
    }

    for (int mi = 0; mi < 4; ++mi) {
        for (int ni = 0; ni < 4; ++ni) {
            int gn = n0 + wCol + ni * 16 + l16;
            float bv = bias[gn];
            for (int r = 0; r < 4; ++r) {
                int gm = m0 + wRow + mi * 16 + quad * 4 + r;
                float v = acc[mi][ni][r] + bv;
                if (MODE == 0) {
                    int b = gm >> 11, s = gm & 2047;
                    int h = gn >> 6, d = gn & 63;
                    ((__bf16*)dstp)[(size_t)z * (MROWS * (size_t)D_MODEL) +
                        ((((size_t)b * NH + h) * SEQ + s) * HD + d)] = (__bf16)v;
                } else {
                    ((float*)dstp)[(size_t)gm * D_MODEL + gn] = v;
                }
            }
        }
    }
}

// ---------------------------------------------------------------------------
// Flash attention, causal. One block per (qblock of 64 rows, head, batch).
// 4 waves; wave w owns q-rows qb*64 + w*16 .. +15. Key tiles of 32.
// Q,K,V in [B,H,S,HD] bf16 (from ws). Output bf16 [B*S, D_MODEL] (to ws).
// ---------------------------------------------------------------------------
__global__ __launch_bounds__(256) void k_attn(
    const __bf16* __restrict__ Q, const __bf16* __restrict__ K,
    const __bf16* __restrict__ V, __bf16* __restrict__ O)
{
    // leading strides are multiples of 8 elems (16 B): aligned ds_read_b128
    alignas(16) __shared__ __bf16 Qs[64 * 72];
    alignas(16) __shared__ __bf16 Ks[32 * 72];
    alignas(16) __shared__ __bf16 Vts[64 * 56];   // V transposed: [d][key]
    alignas(16) __shared__ __bf16 Ps[4][16 * 56]; // per-wave P: [m][key]

    const int tid = threadIdx.x, wid = tid >> 6, lane = tid & 63;
    const int quad = lane >> 4, l16 = lane & 15;
    const int qb = blockIdx.x, h = blockIdx.y, b = blockIdx.z;
    const size_t bh = ((size_t)b * NH + h) * SEQ * HD;
    const __bf16* Qg = Q + bh + (size_t)qb * 64 * HD;
    const __bf16* Kg = K + bh;
    const __bf16* Vg = V + bh;

    // stage Q tile (64x64)
    {
        int row0 = tid >> 3, seg = (tid & 7) * 8;
        for (int it = 0; it < 2; ++it) {
            int row = row0 + it * 32;
            uint4 v = *(const uint4*)&Qg[(size_t)row * HD + seg];
            *(uint4*)&Qs[row * 72 + seg] = v;
        }
    }
    __syncthreads();
    bfrag qf[2];
    qf[0] = *(const bfrag*)&Qs[(wid * 16 + l16) * 72 + 0 + quad * 8];
    qf[1] = *(const bfrag*)&Qs[(wid * 16 + l16) * 72 + 32 + quad * 8];

    const f32x4 zero = {0.f, 0.f, 0.f, 0.f};
    f32x4 o[4];
    for (int dt = 0; dt < 4; ++dt) o[dt] = zero;
    float mrow[4], lrow[4];
    for (int r = 0; r < 4; ++r) { mrow[r] = -__builtin_inff(); lrow[r] = 0.f; }

    const int qrow0 = qb * 64 + wid * 16 + quad * 4; // + r = global q row
    const int kmax = qb * 64 + 63;

    for (int j0 = 0; j0 <= kmax; j0 += 32) {
        __syncthreads(); // protect Ks/Vts from previous iteration's readers
        {
            int row = tid >> 3, seg = (tid & 7) * 8;
            uint4 vk = *(const uint4*)&Kg[(size_t)(j0 + row) * HD + seg];
            *(uint4*)&Ks[row * 72 + seg] = vk;
            union { uint4 u; __bf16 hx[8]; } cv;
            cv.u = *(const uint4*)&Vg[(size_t)(j0 + row) * HD + seg];
            for (int i = 0; i < 8; ++i) Vts[(seg + i) * 56 + row] = cv.hx[i];
        }
        __syncthreads();

        // S = Q * K^T  (16 q-rows x 32 keys per wave)
        f32x4 s[2];
        s[0] = zero; s[1] = zero;
        for (int nt = 0; nt < 2; ++nt) {
            bfrag kf0 = *(const bfrag*)&Ks[(nt * 16 + l16) * 72 + 0 + quad * 8];
            bfrag kf1 = *(const bfrag*)&Ks[(nt * 16 + l16) * 72 + 32 + quad * 8];
            s[nt] = MFMA(qf[0], kf0, s[nt]);
            s[nt] = MFMA(qf[1], kf1, s[nt]);
        }

        // online softmax (per q-row r; cols live in the 16 lanes of this quad)
        for (int r = 0; r < 4; ++r) {
            int q = qrow0 + r;
            float v0 = (j0 + l16      <= q) ? s[0][r] * 0.125f : -__builtin_inff();
            float v1 = (j0 + 16 + l16 <= q) ? s[1][r] * 0.125f : -__builtin_inff();
            float mx = fmaxf(v0, v1);
            for (int off = 1; off < 16; off <<= 1) mx = fmaxf(mx, __shfl_xor(mx, off, 64));
            float mnew = fmaxf(mrow[r], mx);
            float alpha = __expf(mrow[r] - mnew);
            mrow[r] = mnew;
            float p0 = __expf(v0 - mnew), p1 = __expf(v1 - mnew);
            float rs = p0 + p1;
            for (int off = 1; off < 16; off <<= 1) rs += __shfl_xor(rs, off, 64);
            lrow[r] = alpha * lrow[r] + rs;
            Ps[wid][(quad * 4 + r) * 56 + l16] = (__bf16)p0;
            Ps[wid][(quad * 4 + r) * 56 + 16 + l16] = (__bf16)p1;
            for (int dt = 0; dt < 4; ++dt) o[dt][r] *= alpha;
        }
        // drain own-wave LDS writes before re-reading P in A-layout
        asm volatile("s_waitcnt lgkmcnt(0)" ::: "memory");
        bfrag pf = *(const bfrag*)&Ps[wid][l16 * 56 + quad * 8];
        for (int dt = 0; dt < 4; ++dt) {
            bfrag vf = *(const bfrag*)&Vts[(dt * 16 + l16) * 56 + quad * 8];
            o[dt] = MFMA(pf, vf, o[dt]);
        }
    }

    // epilogue: normalize, write to attn_ws [B*S, D_MODEL]
    for (int r = 0; r < 4; ++r) {
        float inv = 1.0f / lrow[r];
        size_t base = ((size_t)b * SEQ + qb * 64 + wid * 16 + quad * 4 + r) * D_MODEL + h * HD;
        for (int dt = 0; dt < 4; ++dt)
            O[base + dt * 16 + l16] = (__bf16)(o[dt][r] * inv);
    }
}

// ---------------------------------------------------------------------------
extern "C" void kernel_launch(void* const* d_in, const int* in_sizes, int n_in,
                              void* d_out, int out_size, void* d_ws, size_t ws_size,
                              hipStream_t stream)
{
    const float* x  = (const float*)d_in[0];
    const float* Wq = (const float*)d_in[1];
    const float* bq = (const float*)d_in[2];
    const float* Wk = (const float*)d_in[3];
    const float* bk = (const float*)d_in[4];
    const float* Wv = (const float*)d_in[5];
    const float* bv = (const float*)d_in[6];
    const float* Wo = (const float*)d_in[7];
    const float* bo = (const float*)d_in[8];

    __bf16* ws = (__bf16*)d_ws;
    const size_t M1 = 1024u * 1024u;          // 1M elems
    __bf16* qkv    = ws;                      // Q,K,V: 3 * 4M bf16 (24 MB)
    __bf16* attn_o = ws + 12 * M1;            // 4M bf16 (8 MB)
    // total 32 MB of ws

    k_gemm128<0><<<dim3(8, 32, 3), 256, 0, stream>>>(x, Wq, Wk, Wv, bq, bk, bv, qkv);
    k_attn<<<dim3(32, 16, 2), 256, 0, stream>>>(qkv, qkv + 4 * M1, qkv + 8 * M1, attn_o);
    k_gemm128<1><<<dim3(8, 32, 1), 256, 0, stream>>>(attn_o, Wo, Wo, Wo, bo, bo, bo,
                                                     (float*)d_out);
}

// Round 5
// 301.667 us; speedup vs baseline: 1.5671x; 1.5671x over previous
//
#include <hip/hip_runtime.h>

typedef __attribute__((ext_vector_type(8))) __bf16 bfrag;
typedef __attribute__((ext_vector_type(4))) float f32x4;

#define MFMA(a, b, c) __builtin_amdgcn_mfma_f32_16x16x32_bf16((a), (b), (c), 0, 0, 0)

#define D_MODEL 1024
#define SEQ     2048
#define NB      2
#define NH      16
#define HD      64
#define MROWS   (NB * SEQ)   // 4096

// log2(e) / sqrt(HD) : fold softmax scale into exp2 domain
#define SCALE_LOG2 0.18033688011112043f

// ---------------------------------------------------------------------------
// Convert x fp32 -> bf16 (4M elems). 2048 blocks x 256 thr x 8 elems.
// ---------------------------------------------------------------------------
__global__ __launch_bounds__(256) void k_cvt_x(
    const float* __restrict__ x, __bf16* __restrict__ xb)
{
    size_t i = ((size_t)blockIdx.x * 256 + threadIdx.x) * 8;
    float4 f0 = *(const float4*)&x[i];
    float4 f1 = *(const float4*)&x[i + 4];
    union { uint4 u; __bf16 h[8]; } cv;
    cv.h[0] = (__bf16)f0.x; cv.h[1] = (__bf16)f0.y;
    cv.h[2] = (__bf16)f0.z; cv.h[3] = (__bf16)f0.w;
    cv.h[4] = (__bf16)f1.x; cv.h[5] = (__bf16)f1.y;
    cv.h[6] = (__bf16)f1.z; cv.h[7] = (__bf16)f1.w;
    *(uint4*)&xb[i] = cv.u;
}

// ---------------------------------------------------------------------------
// Transpose 4 fp32 weights [K=1024][N=1024] -> bf16 [N][K] contiguous.
// ---------------------------------------------------------------------------
__global__ __launch_bounds__(256) void k_transpose4(
    const float* __restrict__ Wq, const float* __restrict__ Wk,
    const float* __restrict__ Wv, const float* __restrict__ Wo,
    __bf16* __restrict__ out)
{
    __shared__ __bf16 t[64][65];
    const float* src = (blockIdx.z == 0) ? Wq : (blockIdx.z == 1) ? Wk
                      : (blockIdx.z == 2) ? Wv : Wo;
    __bf16* dst = out + (size_t)blockIdx.z * (1024u * 1024u);
    int tr = blockIdx.y * 64, tc = blockIdx.x * 64;
    for (int j = 0; j < 16; ++j) {
        int id = threadIdx.x + j * 256;
        int r = id >> 6, c = id & 63;
        t[r][c] = (__bf16)src[(size_t)(tr + r) * 1024 + tc + c];
    }
    __syncthreads();
    for (int j = 0; j < 16; ++j) {
        int id = threadIdx.x + j * 256;
        int r = id >> 6, c = id & 63;
        dst[(size_t)(tc + r) * 1024 + tr + c] = t[c][r];
    }
}

// ---------------------------------------------------------------------------
// GEMM: Y[M=4096][N=1024] = A[M][K=1024] * W + bias. bf16 MFMA internal.
// WT=true : W pre-transposed bf16 [n][k] (vector staging).
// WT=false: W natural fp32 [k][n], transposed+converted during LDS staging.
// MODE 0: A = x (fp32 if !WT, bf16 if WT); dst scatter:
//           z=0/1 -> Q/K bf16 [b,h,s,d];  z=2 -> V bf16 [b,h,d,s] (transposed!)
// MODE 1: A = bf16 attn_o; dst = fp32 row-major [m][n]
// ---------------------------------------------------------------------------
template <int MODE, bool WT>
__global__ __launch_bounds__(256) void k_gemm128(
    const void* __restrict__ Ap,
    const void* __restrict__ W0, const void* __restrict__ W1,
    const void* __restrict__ W2,
    const float* __restrict__ b0, const float* __restrict__ b1,
    const float* __restrict__ b2, void* __restrict__ dstp)
{
    alignas(16) __shared__ __bf16 As[128 * 72];
    alignas(16) __shared__ __bf16 Bs[128 * 72];   // [n][k]

    const int tid = threadIdx.x;
    const int z = blockIdx.z;
    const int m0 = blockIdx.y * 128;
    const int n0 = blockIdx.x * 128;
    const void* W     = (z == 0) ? W0 : (z == 1) ? W1 : W2;
    const float* bias = (z == 0) ? b0 : (z == 1) ? b1 : b2;

    const int wid = tid >> 6, lane = tid & 63;
    const int quad = lane >> 4, l16 = lane & 15;
    const int wRow = (wid >> 1) * 64, wCol = (wid & 1) * 64;

    f32x4 acc[4][4];
    const f32x4 zero = {0.f, 0.f, 0.f, 0.f};
    for (int mi = 0; mi < 4; ++mi)
        for (int ni = 0; ni < 4; ++ni) acc[mi][ni] = zero;

    const int srow = tid >> 3;          // 0..31
    const int sseg = (tid & 7) * 8;     // 0..56
    const int bkrow = tid >> 4;         // 0..15 (fp32 W staging)
    const int bnseg = (tid & 15) * 8;   // 0..120

    for (int k0 = 0; k0 < D_MODEL; k0 += 64) {
        // ---- A tile -> As[m][k] (bf16) ----
        if (MODE == 0 && !WT) {
            const float* A = (const float*)Ap;
            for (int it = 0; it < 4; ++it) {
                int row = srow + it * 32;
                const float* src = &A[(size_t)(m0 + row) * D_MODEL + k0 + sseg];
                float4 f0 = *(const float4*)src;
                float4 f1 = *(const float4*)(src + 4);
                union { uint4 u; __bf16 h[8]; } cv;
                cv.h[0] = (__bf16)f0.x; cv.h[1] = (__bf16)f0.y;
                cv.h[2] = (__bf16)f0.z; cv.h[3] = (__bf16)f0.w;
                cv.h[4] = (__bf16)f1.x; cv.h[5] = (__bf16)f1.y;
                cv.h[6] = (__bf16)f1.z; cv.h[7] = (__bf16)f1.w;
                *(uint4*)&As[row * 72 + sseg] = cv.u;
            }
        } else {
            const __bf16* A = (const __bf16*)Ap;
            for (int it = 0; it < 4; ++it) {
                int row = srow + it * 32;
                uint4 va = *(const uint4*)&A[(size_t)(m0 + row) * D_MODEL + k0 + sseg];
                *(uint4*)&As[row * 72 + sseg] = va;
            }
        }
        // ---- W tile -> Bs[n][k] (bf16) ----
        if (WT) {
            const __bf16* Bt = (const __bf16*)W;
            for (int it = 0; it < 4; ++it) {
                int row = srow + it * 32;
                uint4 vb = *(const uint4*)&Bt[(size_t)(n0 + row) * D_MODEL + k0 + sseg];
                *(uint4*)&Bs[row * 72 + sseg] = vb;
            }
        } else {
            const float* Wf = (const float*)W;
            for (int it = 0; it < 4; ++it) {
                int krow = bkrow + it * 16;
                const float* src = &Wf[(size_t)(k0 + krow) * D_MODEL + n0 + bnseg];
                float4 f0 = *(const float4*)src;
                float4 f1 = *(const float4*)(src + 4);
                Bs[(bnseg + 0) * 72 + krow] = (__bf16)f0.x;
                Bs[(bnseg + 1) * 72 + krow] = (__bf16)f0.y;
                Bs[(bnseg + 2) * 72 + krow] = (__bf16)f0.z;
                Bs[(bnseg + 3) * 72 + krow] = (__bf16)f0.w;
                Bs[(bnseg + 4) * 72 + krow] = (__bf16)f1.x;
                Bs[(bnseg + 5) * 72 + krow] = (__bf16)f1.y;
                Bs[(bnseg + 6) * 72 + krow] = (__bf16)f1.z;
                Bs[(bnseg + 7) * 72 + krow] = (__bf16)f1.w;
            }
        }
        __syncthreads();
        for (int kk = 0; kk < 64; kk += 32) {
            bfrag af[4], bf[4];
            for (int mi = 0; mi < 4; ++mi)
                af[mi] = *(const bfrag*)&As[(wRow + mi * 16 + l16) * 72 + kk + quad * 8];
            for (int ni = 0; ni < 4; ++ni)
                bf[ni] = *(const bfrag*)&Bs[(wCol + ni * 16 + l16) * 72 + kk + quad * 8];
            for (int mi = 0; mi < 4; ++mi)
                for (int ni = 0; ni < 4; ++ni)
                    acc[mi][ni] = MFMA(af[mi], bf[ni], acc[mi][ni]);
        }
        __syncthreads();
    }

    for (int mi = 0; mi < 4; ++mi) {
        for (int ni = 0; ni < 4; ++ni) {
            int gn = n0 + wCol + ni * 16 + l16;
            float bv = bias[gn];
            if (MODE == 0) {
                int gm0 = m0 + wRow + mi * 16 + quad * 4;  // 4-aligned
                int b = gm0 >> 11, s0 = gm0 & 2047;
                int h = gn >> 6, d = gn & 63;
                if (z == 2) {
                    // V transposed: [b,h,d,s] ; 4 consecutive s -> packed b64
                    union { unsigned long long u; __bf16 h4[4]; } pk;
                    for (int r = 0; r < 4; ++r)
                        pk.h4[r] = (__bf16)(acc[mi][ni][r] + bv);
                    __bf16* dst = (__bf16*)dstp + (size_t)2 * (MROWS * (size_t)D_MODEL)
                                + ((((size_t)b * NH + h) * HD + d) * SEQ + s0);
                    *(unsigned long long*)dst = pk.u;
                } else {
                    __bf16* dst = (__bf16*)dstp + (size_t)z * (MROWS * (size_t)D_MODEL);
                    for (int r = 0; r < 4; ++r)
                        dst[(((size_t)b * NH + h) * SEQ + s0 + r) * HD + d] =
                            (__bf16)(acc[mi][ni][r] + bv);
                }
            } else {
                for (int r = 0; r < 4; ++r) {
                    int gm = m0 + wRow + mi * 16 + quad * 4 + r;
                    ((float*)dstp)[(size_t)gm * D_MODEL + gn] = acc[mi][ni][r] + bv;
                }
            }
        }
    }
}

// ---------------------------------------------------------------------------
// Flash attention (causal), S^T formulation. One block per (64-row q-block,
// head, batch); 4 waves, wave w owns q-rows qb*64+w*16..+15; 64-key tiles.
// Q,K bf16 [b,h,s,d]; Vt bf16 [b,h,d,s]. Output bf16 [B*S, D_MODEL] to ws.
//
// S^T = MFMA(A=K, B=Q): C col(l16)=q-row, row(quad*4+r)=key -> softmax is
// per-lane over 16 reg scores + 2 cross-quad shuffles. P^T lane-packs 4
// consecutive keys -> single ds_write_b64. O = MFMA(A=P, B=Vt).
// ---------------------------------------------------------------------------
__global__ __launch_bounds__(256) void k_attn(
    const __bf16* __restrict__ Q, const __bf16* __restrict__ K,
    const __bf16* __restrict__ Vt, __bf16* __restrict__ O)
{
    alignas(16) __shared__ __bf16 Qs[64 * 72];
    alignas(16) __shared__ __bf16 Ks[64 * 72];
    alignas(16) __shared__ __bf16 Vts[64 * 72];    // [d][key]
    alignas(16) __shared__ __bf16 Ps[4][16 * 72];  // per-wave P: [qrow][key]

    const int tid = threadIdx.x, wid = tid >> 6, lane = tid & 63;
    const int quad = lane >> 4, l16 = lane & 15;
    const int qb = blockIdx.x, h = blockIdx.y, b = blockIdx.z;
    const size_t bh = ((size_t)b * NH + h) * SEQ * HD;
    const __bf16* Qg  = Q + bh + (size_t)qb * 64 * HD;
    const __bf16* Kg  = K + bh;
    const __bf16* Vtg = Vt + ((size_t)b * NH + h) * HD * SEQ;  // [d][s]

    const int row0 = tid >> 3, seg = (tid & 7) * 8;

    // stage Q tile (64 rows x 64 d)
    for (int it = 0; it < 2; ++it) {
        int row = row0 + it * 32;
        *(uint4*)&Qs[row * 72 + seg] = *(const uint4*)&Qg[(size_t)row * HD + seg];
    }
    __syncthreads();
    bfrag qf[2];
    qf[0] = *(const bfrag*)&Qs[(wid * 16 + l16) * 72 + 0 + quad * 8];
    qf[1] = *(const bfrag*)&Qs[(wid * 16 + l16) * 72 + 32 + quad * 8];

    const f32x4 zero = {0.f, 0.f, 0.f, 0.f};
    f32x4 o[4];
    for (int dt = 0; dt < 4; ++dt) o[dt] = zero;
    float mrow = -__builtin_inff(), lrow = 0.f;   // this lane's q-row = q below
    const int q = qb * 64 + wid * 16 + l16;
    const int srcbase = (lane & 48) + quad * 4;   // shfl source for row quad*4+r
    const int ntile = qb + 1;

    for (int t = 0; t < ntile; ++t) {
        const int j0 = t * 64;
        __syncthreads();
        for (int it = 0; it < 2; ++it) {
            int row = row0 + it * 32;
            *(uint4*)&Ks[row * 72 + seg] =
                *(const uint4*)&Kg[(size_t)(j0 + row) * HD + seg];
            *(uint4*)&Vts[row * 72 + seg] =
                *(const uint4*)&Vtg[(size_t)row * SEQ + j0 + seg];
        }
        __syncthreads();

        // S^T tiles: st[kt] -> key = j0+kt*16+quad*4+r, qrow = q (lane l16)
        f32x4 st[4];
        for (int kt = 0; kt < 4; ++kt) {
            bfrag ka0 = *(const bfrag*)&Ks[(kt * 16 + l16) * 72 + 0 + quad * 8];
            bfrag ka1 = *(const bfrag*)&Ks[(kt * 16 + l16) * 72 + 32 + quad * 8];
            st[kt] = MFMA(ka1, qf[1], MFMA(ka0, qf[0], zero));
        }

        // softmax in log2 domain (scale folded)
        const bool lastt = (t == ntile - 1);
        float sc[4][4];
        float mloc = -__builtin_inff();
        for (int kt = 0; kt < 4; ++kt)
            for (int r = 0; r < 4; ++r) {
                float v = st[kt][r] * SCALE_LOG2;
                if (lastt && (j0 + kt * 16 + quad * 4 + r > q)) v = -__builtin_inff();
                sc[kt][r] = v;
                mloc = fmaxf(mloc, v);
            }
        float m2 = fmaxf(mloc, __shfl_xor(mloc, 16, 64));
        m2 = fmaxf(m2, __shfl_xor(m2, 32, 64));
        float mnew = fmaxf(mrow, m2);
        float alpha = exp2f(mrow - mnew);
        mrow = mnew;
        float sloc = 0.f;
        float p[4][4];
        for (int kt = 0; kt < 4; ++kt)
            for (int r = 0; r < 4; ++r) {
                p[kt][r] = exp2f(sc[kt][r] - mnew);
                sloc += p[kt][r];
            }
        float s2 = sloc + __shfl_xor(sloc, 16, 64);
        s2 = s2 + __shfl_xor(s2, 32, 64);
        lrow = alpha * lrow + s2;

        // P^T -> Ps[wid][qrow=l16][key]: pack 4 consecutive keys per write
        for (int kt = 0; kt < 4; ++kt) {
            union { unsigned long long u; __bf16 h4[4]; } pk;
            for (int r = 0; r < 4; ++r) pk.h4[r] = (__bf16)p[kt][r];
            *(unsigned long long*)&Ps[wid][l16 * 72 + kt * 16 + quad * 4] = pk.u;
        }
        asm volatile("s_waitcnt lgkmcnt(0)" ::: "memory");

        // rescale o (alpha indexed by qrow quad*4+r -> gather via shfl)
        for (int r = 0; r < 4; ++r) {
            float ar = __shfl(alpha, srcbase + r, 64);
            for (int dt = 0; dt < 4; ++dt) o[dt][r] *= ar;
        }

        // O += P * V : A = Ps[qrow][key], B = Vts[d][key]
        for (int c = 0; c < 2; ++c) {
            bfrag pf = *(const bfrag*)&Ps[wid][l16 * 72 + c * 32 + quad * 8];
            for (int dt = 0; dt < 4; ++dt) {
                bfrag vf = *(const bfrag*)&Vts[(dt * 16 + l16) * 72 + c * 32 + quad * 8];
                o[dt] = MFMA(pf, vf, o[dt]);
            }
        }
    }

    // epilogue: normalize (gather lrow per C-row), write [B*S, D_MODEL]
    for (int r = 0; r < 4; ++r) {
        float lr = __shfl(lrow, srcbase + r, 64);
        float inv = 1.0f / lr;
        size_t base = ((size_t)b * SEQ + qb * 64 + wid * 16 + quad * 4 + r) * D_MODEL
                    + (size_t)h * HD;
        for (int dt = 0; dt < 4; ++dt)
            O[base + dt * 16 + l16] = (__bf16)(o[dt][r] * inv);
    }
}

// ---------------------------------------------------------------------------
extern "C" void kernel_launch(void* const* d_in, const int* in_sizes, int n_in,
                              void* d_out, int out_size, void* d_ws, size_t ws_size,
                              hipStream_t stream)
{
    const float* x  = (const float*)d_in[0];
    const float* Wq = (const float*)d_in[1];
    const float* bq = (const float*)d_in[2];
    const float* Wk = (const float*)d_in[3];
    const float* bk = (const float*)d_in[4];
    const float* Wv = (const float*)d_in[5];
    const float* bv = (const float*)d_in[6];
    const float* Wo = (const float*)d_in[7];
    const float* bo = (const float*)d_in[8];

    __bf16* ws = (__bf16*)d_ws;
    const size_t M1 = 1024u * 1024u;          // 1M elems
    __bf16* qkv    = ws;                      // Q @0, K @4M, Vt @8M (24 MB)
    __bf16* attn_o = ws + 12 * M1;            // 4M (8 MB)
    __bf16* Wt     = ws + 16 * M1;            // 4M bf16 transposed weights (8 MB)
    __bf16* xb     = ws + 20 * M1;            // 4M bf16 x (8 MB) -> 48 MB total

    const bool fast = ws_size >= (size_t)48 * 1024 * 1024;

    if (fast) {
        k_cvt_x<<<2048, 256, 0, stream>>>(x, xb);
        k_transpose4<<<dim3(16, 16, 4), 256, 0, stream>>>(Wq, Wk, Wv, Wo, Wt);
        k_gemm128<0, true><<<dim3(8, 32, 3), 256, 0, stream>>>(
            xb, Wt, Wt + M1, Wt + 2 * M1, bq, bk, bv, qkv);
        k_attn<<<dim3(32, 16, 2), 256, 0, stream>>>(
            qkv, qkv + 4 * M1, qkv + 8 * M1, attn_o);
        k_gemm128<1, true><<<dim3(8, 32, 1), 256, 0, stream>>>(
            attn_o, Wt + 3 * M1, Wt + 3 * M1, Wt + 3 * M1, bo, bo, bo, (float*)d_out);
    } else {
        k_gemm128<0, false><<<dim3(8, 32, 3), 256, 0, stream>>>(
            x, Wq, Wk, Wv, bq, bk, bv, qkv);
        k_attn<<<dim3(32, 16, 2), 256, 0, stream>>>(
            qkv, qkv + 4 * M1, qkv + 8 * M1, attn_o);
        k_gemm128<1, false><<<dim3(8, 32, 1), 256, 0, stream>>>(
            attn_o, Wo, Wo, Wo, bo, bo, bo, (float*)d_out);
    }
}

// Round 6
// 241.043 us; speedup vs baseline: 1.9612x; 1.2515x over previous
//
#include <hip/hip_runtime.h>

typedef __attribute__((ext_vector_type(8))) __bf16 bfrag;
typedef __attribute__((ext_vector_type(4))) float f32x4;

#define MFMA(a, b, c) __builtin_amdgcn_mfma_f32_16x16x32_bf16((a), (b), (c), 0, 0, 0)

#define D_MODEL 1024
#define SEQ     2048
#define NB      2
#define NH      16
#define HD      64
#define MROWS   (NB * SEQ)   // 4096

// log2(e) / sqrt(HD) : folded into Q at the QKV-GEMM epilogue
#define SCALE_LOG2 0.18033688011112043f
#define NEG_BIG    (-3.0e38f)

#define GLOBAL_AS(p) ((const __attribute__((address_space(1))) void*)(p))
#define LDS_AS(p)    ((__attribute__((address_space(3))) void*)(p))
#define ASYNC_CP16(g, l) __builtin_amdgcn_global_load_lds(GLOBAL_AS(g), LDS_AS(l), 16, 0, 0)

// ---------------------------------------------------------------------------
__global__ __launch_bounds__(256) void k_cvt_x(
    const float* __restrict__ x, __bf16* __restrict__ xb)
{
    size_t i = ((size_t)blockIdx.x * 256 + threadIdx.x) * 8;
    float4 f0 = *(const float4*)&x[i];
    float4 f1 = *(const float4*)&x[i + 4];
    union { uint4 u; __bf16 h[8]; } cv;
    cv.h[0] = (__bf16)f0.x; cv.h[1] = (__bf16)f0.y;
    cv.h[2] = (__bf16)f0.z; cv.h[3] = (__bf16)f0.w;
    cv.h[4] = (__bf16)f1.x; cv.h[5] = (__bf16)f1.y;
    cv.h[6] = (__bf16)f1.z; cv.h[7] = (__bf16)f1.w;
    *(uint4*)&xb[i] = cv.u;
}

// ---------------------------------------------------------------------------
__global__ __launch_bounds__(256) void k_transpose4(
    const float* __restrict__ Wq, const float* __restrict__ Wk,
    const float* __restrict__ Wv, const float* __restrict__ Wo,
    __bf16* __restrict__ out)
{
    __shared__ __bf16 t[64][65];
    const float* src = (blockIdx.z == 0) ? Wq : (blockIdx.z == 1) ? Wk
                      : (blockIdx.z == 2) ? Wv : Wo;
    __bf16* dst = out + (size_t)blockIdx.z * (1024u * 1024u);
    int tr = blockIdx.y * 64, tc = blockIdx.x * 64;
    for (int j = 0; j < 16; ++j) {
        int id = threadIdx.x + j * 256;
        int r = id >> 6, c = id & 63;
        t[r][c] = (__bf16)src[(size_t)(tr + r) * 1024 + tc + c];
    }
    __syncthreads();
    for (int j = 0; j < 16; ++j) {
        int id = threadIdx.x + j * 256;
        int r = id >> 6, c = id & 63;
        dst[(size_t)(tc + r) * 1024 + tr + c] = t[c][r];
    }
}

// ---------------------------------------------------------------------------
// GEMM: Y[4096][1024] = A * W + bias (bf16 MFMA).
// WT=true : A bf16, W pre-transposed bf16 [n][k] -> global_load_lds staging,
//           unpadded LDS (m97 recipe).
// WT=false: A fp32 (MODE 0) / bf16 (MODE 1), W fp32 [k][n] -> manual staging.
// MODE 0: z=0 -> Q bf16 [b,h,s,d] pre-scaled by SCALE_LOG2; z=1 -> K;
//         z=2 -> V bf16 [b,h,d,s] (transposed).
// MODE 1: dst fp32 row-major.
// ---------------------------------------------------------------------------
template <int MODE, bool WT>
__global__ __launch_bounds__(256) void k_gemm128(
    const void* __restrict__ Ap,
    const void* __restrict__ W0, const void* __restrict__ W1,
    const void* __restrict__ W2,
    const float* __restrict__ b0, const float* __restrict__ b1,
    const float* __restrict__ b2, void* __restrict__ dstp)
{
    constexpr int AST = WT ? 64 : 72;
    alignas(16) __shared__ __bf16 As[128 * AST];
    alignas(16) __shared__ __bf16 Bs[128 * AST];

    const int tid = threadIdx.x;
    const int z = blockIdx.z;
    const int m0 = blockIdx.y * 128;
    const int n0 = blockIdx.x * 128;
    const void* W     = (z == 0) ? W0 : (z == 1) ? W1 : W2;
    const float* bias = (z == 0) ? b0 : (z == 1) ? b1 : b2;

    const int wid = tid >> 6, lane = tid & 63;
    const int quad = lane >> 4, l16 = lane & 15;
    const int wRow = (wid >> 1) * 64, wCol = (wid & 1) * 64;

    f32x4 acc[4][4];
    const f32x4 zero = {0.f, 0.f, 0.f, 0.f};
    for (int mi = 0; mi < 4; ++mi)
        for (int ni = 0; ni < 4; ++ni) acc[mi][ni] = zero;

    const int srow = tid >> 3;          // 0..31 (manual staging)
    const int sseg = (tid & 7) * 8;
    const int bkrow = tid >> 4;         // 0..15 (fp32 W staging)
    const int bnseg = (tid & 15) * 8;
    const int lrow = lane >> 3;         // 0..7 (async staging)
    const int lseg = (lane & 7) * 8;

    for (int k0 = 0; k0 < D_MODEL; k0 += 64) {
        __syncthreads();                // readers of previous tile done
        if (WT) {
            const __bf16* Ab = (const __bf16*)Ap;
            const __bf16* Bt = (const __bf16*)W;
            for (int it = 0; it < 4; ++it) {
                int row = wid * 32 + it * 8;   // wave-uniform LDS base
                ASYNC_CP16(&Ab[(size_t)(m0 + row + lrow) * D_MODEL + k0 + lseg],
                           &As[row * 64]);
                ASYNC_CP16(&Bt[(size_t)(n0 + row + lrow) * D_MODEL + k0 + lseg],
                           &Bs[row * 64]);
            }
        } else {
            if (MODE == 0) {
                const float* A = (const float*)Ap;
                for (int it = 0; it < 4; ++it) {
                    int row = srow + it * 32;
                    const float* src = &A[(size_t)(m0 + row) * D_MODEL + k0 + sseg];
                    float4 f0 = *(const float4*)src;
                    float4 f1 = *(const float4*)(src + 4);
                    union { uint4 u; __bf16 h[8]; } cv;
                    cv.h[0] = (__bf16)f0.x; cv.h[1] = (__bf16)f0.y;
                    cv.h[2] = (__bf16)f0.z; cv.h[3] = (__bf16)f0.w;
                    cv.h[4] = (__bf16)f1.x; cv.h[5] = (__bf16)f1.y;
                    cv.h[6] = (__bf16)f1.z; cv.h[7] = (__bf16)f1.w;
                    *(uint4*)&As[row * AST + sseg] = cv.u;
                }
            } else {
                const __bf16* A = (const __bf16*)Ap;
                for (int it = 0; it < 4; ++it) {
                    int row = srow + it * 32;
                    uint4 va = *(const uint4*)&A[(size_t)(m0 + row) * D_MODEL + k0 + sseg];
                    *(uint4*)&As[row * AST + sseg] = va;
                }
            }
            const float* Wf = (const float*)W;
            for (int it = 0; it < 4; ++it) {
                int krow = bkrow + it * 16;
                const float* src = &Wf[(size_t)(k0 + krow) * D_MODEL + n0 + bnseg];
                float4 f0 = *(const float4*)src;
                float4 f1 = *(const float4*)(src + 4);
                Bs[(bnseg + 0) * AST + krow] = (__bf16)f0.x;
                Bs[(bnseg + 1) * AST + krow] = (__bf16)f0.y;
                Bs[(bnseg + 2) * AST + krow] = (__bf16)f0.z;
                Bs[(bnseg + 3) * AST + krow] = (__bf16)f0.w;
                Bs[(bnseg + 4) * AST + krow] = (__bf16)f1.x;
                Bs[(bnseg + 5) * AST + krow] = (__bf16)f1.y;
                Bs[(bnseg + 6) * AST + krow] = (__bf16)f1.z;
                Bs[(bnseg + 7) * AST + krow] = (__bf16)f1.w;
            }
        }
        __syncthreads();                // drains vmcnt (async LDS) + lgkm
        for (int kk = 0; kk < 64; kk += 32) {
            bfrag af[4], bf[4];
            for (int mi = 0; mi < 4; ++mi)
                af[mi] = *(const bfrag*)&As[(wRow + mi * 16 + l16) * AST + kk + quad * 8];
            for (int ni = 0; ni < 4; ++ni)
                bf[ni] = *(const bfrag*)&Bs[(wCol + ni * 16 + l16) * AST + kk + quad * 8];
            for (int mi = 0; mi < 4; ++mi)
                for (int ni = 0; ni < 4; ++ni)
                    acc[mi][ni] = MFMA(af[mi], bf[ni], acc[mi][ni]);
        }
    }

    for (int mi = 0; mi < 4; ++mi) {
        for (int ni = 0; ni < 4; ++ni) {
            int gn = n0 + wCol + ni * 16 + l16;
            float bv = bias[gn];
            if (MODE == 0) {
                int gm0 = m0 + wRow + mi * 16 + quad * 4;  // 4-aligned
                int b = gm0 >> 11, s0 = gm0 & 2047;
                int h = gn >> 6, d = gn & 63;
                if (z == 2) {
                    // V transposed: [b,h,d,s]; 4 consecutive s -> packed b64
                    union { unsigned long long u; __bf16 h4[4]; } pk;
                    for (int r = 0; r < 4; ++r)
                        pk.h4[r] = (__bf16)(acc[mi][ni][r] + bv);
                    __bf16* dst = (__bf16*)dstp + (size_t)2 * (MROWS * (size_t)D_MODEL)
                                + ((((size_t)b * NH + h) * HD + d) * SEQ + s0);
                    *(unsigned long long*)dst = pk.u;
                } else {
                    __bf16* dst = (__bf16*)dstp + (size_t)z * (MROWS * (size_t)D_MODEL);
                    for (int r = 0; r < 4; ++r) {
                        float v = acc[mi][ni][r] + bv;
                        if (z == 0) v *= SCALE_LOG2;   // fold softmax scale into Q
                        dst[(((size_t)b * NH + h) * SEQ + s0 + r) * HD + d] = (__bf16)v;
                    }
                }
            } else {
                for (int r = 0; r < 4; ++r) {
                    int gm = m0 + wRow + mi * 16 + quad * 4 + r;
                    ((float*)dstp)[(size_t)gm * D_MODEL + gn] = acc[mi][ni][r] + bv;
                }
            }
        }
    }
}

// ---------------------------------------------------------------------------
// Flash attention (causal), S^T formulation, register-prefetch pipelined.
// Block = (64 q-rows, head, batch), 4 waves x 16 q-rows, 64-key tiles.
// Q (pre-scaled by log2e/sqrt(HD)) & K bf16 [b,h,s,d]; Vt bf16 [b,h,d,s].
// qb swizzle: a CU's 4 resident blocks get qb offsets {0,8,16,24} -> balanced.
// LDS 27.6 KB -> 5 blocks/CU.
// ---------------------------------------------------------------------------
__global__ __launch_bounds__(256) void k_attn(
    const __bf16* __restrict__ Q, const __bf16* __restrict__ K,
    const __bf16* __restrict__ Vt, __bf16* __restrict__ O)
{
    alignas(16) __shared__ __bf16 Ks[64 * 72];
    alignas(16) __shared__ __bf16 Vts[64 * 72];    // [d][key]
    alignas(16) __shared__ __bf16 Ps[4][16 * 72];  // per-wave P^T: [qrow][key]

    const int tid = threadIdx.x, wid = tid >> 6, lane = tid & 63;
    const int quad = lane >> 4, l16 = lane & 15;
    const int qb = (blockIdx.x + blockIdx.y + 16 * blockIdx.z) & 31;
    const int h = blockIdx.y, b = blockIdx.z;
    const size_t bh = ((size_t)b * NH + h) * SEQ * HD;
    const __bf16* Qg  = Q + bh + (size_t)qb * 64 * HD;
    const __bf16* Kg  = K + bh;
    const __bf16* Vtg = Vt + ((size_t)b * NH + h) * HD * SEQ;  // [d][s]

    // Q fragments straight from global (per-lane contiguous 16 B)
    bfrag qf[2];
    qf[0] = *(const bfrag*)&Qg[(size_t)(wid * 16 + l16) * HD + quad * 8];
    qf[1] = *(const bfrag*)&Qg[(size_t)(wid * 16 + l16) * HD + 32 + quad * 8];

    const f32x4 zero = {0.f, 0.f, 0.f, 0.f};
    f32x4 o[4];
    for (int dt = 0; dt < 4; ++dt) o[dt] = zero;
    float mrow = NEG_BIG, lrow = 0.f;             // this lane's q-row state
    const int q = qb * 64 + wid * 16 + l16;
    const int srcbase = (lane & 48) + quad * 4;   // shfl src for C-row quad*4+r
    const int ntile = qb + 1;

    const int row0 = tid >> 3, seg = (tid & 7) * 8;

    // prefetch tile 0 into registers
    uint4 kreg0 = *(const uint4*)&Kg[(size_t)row0 * HD + seg];
    uint4 kreg1 = *(const uint4*)&Kg[(size_t)(row0 + 32) * HD + seg];
    uint4 vreg0 = *(const uint4*)&Vtg[(size_t)row0 * SEQ + seg];
    uint4 vreg1 = *(const uint4*)&Vtg[(size_t)(row0 + 32) * SEQ + seg];

    for (int t = 0; t < ntile; ++t) {
        const int j0 = t * 64;
        __syncthreads();   // all waves done reading previous tile's LDS
        *(uint4*)&Ks[row0 * 72 + seg] = kreg0;
        *(uint4*)&Ks[(row0 + 32) * 72 + seg] = kreg1;
        *(uint4*)&Vts[row0 * 72 + seg] = vreg0;
        *(uint4*)&Vts[(row0 + 32) * 72 + seg] = vreg1;
        if (t + 1 < ntile) {           // issue async loads for next tile
            const int j1 = j0 + 64;
            kreg0 = *(const uint4*)&Kg[(size_t)(j1 + row0) * HD + seg];
            kreg1 = *(const uint4*)&Kg[(size_t)(j1 + row0 + 32) * HD + seg];
            vreg0 = *(const uint4*)&Vtg[(size_t)row0 * SEQ + j1 + seg];
            vreg1 = *(const uint4*)&Vtg[(size_t)(row0 + 32) * SEQ + j1 + seg];
        }
        __syncthreads();   // tile t LDS ready

        // S^T: key = j0+kt*16+quad*4+r (C-row), qrow = q (C-col l16)
        f32x4 st[4];
        for (int kt = 0; kt < 4; ++kt) {
            bfrag ka0 = *(const bfrag*)&Ks[(kt * 16 + l16) * 72 + quad * 8];
            bfrag ka1 = *(const bfrag*)&Ks[(kt * 16 + l16) * 72 + 32 + quad * 8];
            st[kt] = MFMA(ka1, qf[1], MFMA(ka0, qf[0], zero));
        }

        // online softmax (scores already in log2 domain; mask only diagonal)
        float mloc = NEG_BIG;
        if (t == ntile - 1) {
            for (int kt = 0; kt < 4; ++kt)
                for (int r = 0; r < 4; ++r) {
                    float v = (j0 + kt * 16 + quad * 4 + r > q) ? NEG_BIG : st[kt][r];
                    st[kt][r] = v;
                    mloc = fmaxf(mloc, v);
                }
        } else {
            for (int kt = 0; kt < 4; ++kt)
                for (int r = 0; r < 4; ++r) mloc = fmaxf(mloc, st[kt][r]);
        }
        float m2 = fmaxf(mloc, __shfl_xor(mloc, 16, 64));
        m2 = fmaxf(m2, __shfl_xor(m2, 32, 64));
        float mnew = fmaxf(mrow, m2);
        float alpha = exp2f(mrow - mnew);
        mrow = mnew;
        float sloc = 0.f;
        for (int kt = 0; kt < 4; ++kt)
            for (int r = 0; r < 4; ++r) {
                float p = exp2f(st[kt][r] - mnew);
                st[kt][r] = p;
                sloc += p;
            }
        float s2 = sloc + __shfl_xor(sloc, 16, 64);
        s2 = s2 + __shfl_xor(s2, 32, 64);
        lrow = alpha * lrow + s2;

        // P^T -> Ps[wid][qrow=l16][key]: 4 consecutive keys per b64 write
        for (int kt = 0; kt < 4; ++kt) {
            union { unsigned long long u; __bf16 h4[4]; } pk;
            for (int r = 0; r < 4; ++r) pk.h4[r] = (__bf16)st[kt][r];
            *(unsigned long long*)&Ps[wid][l16 * 72 + kt * 16 + quad * 4] = pk.u;
        }
        asm volatile("s_waitcnt lgkmcnt(0)" ::: "memory");

        // rescale o (alpha per C-row gathered via shfl)
        for (int r = 0; r < 4; ++r) {
            float ar = __shfl(alpha, srcbase + r, 64);
            for (int dt = 0; dt < 4; ++dt) o[dt][r] *= ar;
        }

        // O += P * V : A = Ps[qrow][key], B = Vts[d][key]
        for (int c = 0; c < 2; ++c) {
            bfrag pf = *(const bfrag*)&Ps[wid][l16 * 72 + c * 32 + quad * 8];
            for (int dt = 0; dt < 4; ++dt) {
                bfrag vf = *(const bfrag*)&Vts[(dt * 16 + l16) * 72 + c * 32 + quad * 8];
                o[dt] = MFMA(pf, vf, o[dt]);
            }
        }
    }

    // epilogue: normalize (lrow per C-row via shfl), write [B*S, D_MODEL]
    for (int r = 0; r < 4; ++r) {
        float lr = __shfl(lrow, srcbase + r, 64);
        float inv = 1.0f / lr;
        size_t base = ((size_t)b * SEQ + qb * 64 + wid * 16 + quad * 4 + r) * D_MODEL
                    + (size_t)h * HD;
        for (int dt = 0; dt < 4; ++dt)
            O[base + dt * 16 + l16] = (__bf16)(o[dt][r] * inv);
    }
}

// ---------------------------------------------------------------------------
extern "C" void kernel_launch(void* const* d_in, const int* in_sizes, int n_in,
                              void* d_out, int out_size, void* d_ws, size_t ws_size,
                              hipStream_t stream)
{
    const float* x  = (const float*)d_in[0];
    const float* Wq = (const float*)d_in[1];
    const float* bq = (const float*)d_in[2];
    const float* Wk = (const float*)d_in[3];
    const float* bk = (const float*)d_in[4];
    const float* Wv = (const float*)d_in[5];
    const float* bv = (const float*)d_in[6];
    const float* Wo = (const float*)d_in[7];
    const float* bo = (const float*)d_in[8];

    __bf16* ws = (__bf16*)d_ws;
    const size_t M1 = 1024u * 1024u;          // 1M elems
    __bf16* qkv    = ws;                      // Q @0, K @4M, Vt @8M (24 MB)
    __bf16* attn_o = ws + 12 * M1;            // 4M (8 MB)
    __bf16* Wt     = ws + 16 * M1;            // 4M bf16 transposed weights (8 MB)
    __bf16* xb     = ws + 20 * M1;            // 4M bf16 x (8 MB) -> 48 MB total

    const bool fast = ws_size >= (size_t)48 * 1024 * 1024;

    if (fast) {
        k_cvt_x<<<2048, 256, 0, stream>>>(x, xb);
        k_transpose4<<<dim3(16, 16, 4), 256, 0, stream>>>(Wq, Wk, Wv, Wo, Wt);
        k_gemm128<0, true><<<dim3(8, 32, 3), 256, 0, stream>>>(
            xb, Wt, Wt + M1, Wt + 2 * M1, bq, bk, bv, qkv);
        k_attn<<<dim3(32, 16, 2), 256, 0, stream>>>(
            qkv, qkv + 4 * M1, qkv + 8 * M1, attn_o);
        k_gemm128<1, true><<<dim3(8, 32, 1), 256, 0, stream>>>(
            attn_o, Wt + 3 * M1, Wt + 3 * M1, Wt + 3 * M1, bo, bo, bo, (float*)d_out);
    } else {
        k_gemm128<0, false><<<dim3(8, 32, 3), 256, 0, stream>>>(
            x, Wq, Wk, Wv, bq, bk, bv, qkv);
        k_attn<<<dim3(32, 16, 2), 256, 0, stream>>>(
            qkv, qkv + 4 * M1, qkv + 8 * M1, attn_o);
        k_gemm128<1, false><<<dim3(8, 32, 1), 256, 0, stream>>>(
            attn_o, Wo, Wo, Wo, bo, bo, bo, (float*)d_out);
    }
}

// Round 7
// 240.454 us; speedup vs baseline: 1.9660x; 1.0024x over previous
//
#include <hip/hip_runtime.h>

typedef __attribute__((ext_vector_type(8))) __bf16 bfrag;
typedef __attribute__((ext_vector_type(4))) float f32x4;

#define MFMA(a, b, c) __builtin_amdgcn_mfma_f32_16x16x32_bf16((a), (b), (c), 0, 0, 0)

#define D_MODEL 1024
#define SEQ     2048
#define NB      2
#define NH      16
#define HD      64
#define MROWS   (NB * SEQ)   // 4096

// log2(e) / sqrt(HD) : folded into Q at the QKV-GEMM epilogue
#define SCALE_LOG2 0.18033688011112043f
#define NEG_BIG    (-3.0e38f)

#define GLOBAL_AS(p) ((const __attribute__((address_space(1))) void*)(p))
#define LDS_AS(p)    ((__attribute__((address_space(3))) void*)(p))
#define ASYNC_CP16(g, l) __builtin_amdgcn_global_load_lds(GLOBAL_AS(g), LDS_AS(l), 16, 0, 0)

// ---------------------------------------------------------------------------
__global__ __launch_bounds__(256) void k_cvt_x(
    const float* __restrict__ x, __bf16* __restrict__ xb)
{
    size_t i = ((size_t)blockIdx.x * 256 + threadIdx.x) * 8;
    float4 f0 = *(const float4*)&x[i];
    float4 f1 = *(const float4*)&x[i + 4];
    union { uint4 u; __bf16 h[8]; } cv;
    cv.h[0] = (__bf16)f0.x; cv.h[1] = (__bf16)f0.y;
    cv.h[2] = (__bf16)f0.z; cv.h[3] = (__bf16)f0.w;
    cv.h[4] = (__bf16)f1.x; cv.h[5] = (__bf16)f1.y;
    cv.h[6] = (__bf16)f1.z; cv.h[7] = (__bf16)f1.w;
    *(uint4*)&xb[i] = cv.u;
}

// ---------------------------------------------------------------------------
__global__ __launch_bounds__(256) void k_transpose4(
    const float* __restrict__ Wq, const float* __restrict__ Wk,
    const float* __restrict__ Wv, const float* __restrict__ Wo,
    __bf16* __restrict__ out)
{
    __shared__ __bf16 t[64][65];
    const float* src = (blockIdx.z == 0) ? Wq : (blockIdx.z == 1) ? Wk
                      : (blockIdx.z == 2) ? Wv : Wo;
    __bf16* dst = out + (size_t)blockIdx.z * (1024u * 1024u);
    int tr = blockIdx.y * 64, tc = blockIdx.x * 64;
    for (int j = 0; j < 16; ++j) {
        int id = threadIdx.x + j * 256;
        int r = id >> 6, c = id & 63;
        t[r][c] = (__bf16)src[(size_t)(tr + r) * 1024 + tc + c];
    }
    __syncthreads();
    for (int j = 0; j < 16; ++j) {
        int id = threadIdx.x + j * 256;
        int r = id >> 6, c = id & 63;
        dst[(size_t)(tc + r) * 1024 + tr + c] = t[c][r];
    }
}

// ---------------------------------------------------------------------------
// GEMM: Y[4096][1024] = A * W + bias (bf16 MFMA).
// WT=true : A bf16, W pre-transposed bf16 [n][k]. global_load_lds width-16
//           staging into XOR-swizzled unpadded LDS (stride 64):
//           element (row, k) lives at [row*64 + (k ^ ((row&7)*8))] — the
//           swizzle is absorbed into the per-lane GLOBAL source address
//           (LDS dest of global_load_lds is lane-contiguous). Frag reads
//           XOR with (l16&7)*8 -> max 2-way bank aliasing (free).
// WT=false: A fp32 (MODE 0) / bf16 (MODE 1), W fp32 [k][n] -> manual staging,
//           padded stride 72.
// MODE 0: z=0 -> Q bf16 [b,h,s,d] pre-scaled by SCALE_LOG2; z=1 -> K;
//         z=2 -> V bf16 [b,h,d,s] (transposed).
// MODE 1: dst fp32 row-major.
// ---------------------------------------------------------------------------
template <int MODE, bool WT>
__global__ __launch_bounds__(256) void k_gemm128(
    const void* __restrict__ Ap,
    const void* __restrict__ W0, const void* __restrict__ W1,
    const void* __restrict__ W2,
    const float* __restrict__ b0, const float* __restrict__ b1,
    const float* __restrict__ b2, void* __restrict__ dstp)
{
    constexpr int AST = WT ? 64 : 72;
    alignas(16) __shared__ __bf16 As[128 * AST];
    alignas(16) __shared__ __bf16 Bs[128 * AST];

    const int tid = threadIdx.x;
    const int z = blockIdx.z;
    const int m0 = blockIdx.y * 128;
    const int n0 = blockIdx.x * 128;
    const void* W     = (z == 0) ? W0 : (z == 1) ? W1 : W2;
    const float* bias = (z == 0) ? b0 : (z == 1) ? b1 : b2;

    const int wid = tid >> 6, lane = tid & 63;
    const int quad = lane >> 4, l16 = lane & 15;
    const int wRow = (wid >> 1) * 64, wCol = (wid & 1) * 64;

    f32x4 acc[4][4];
    const f32x4 zero = {0.f, 0.f, 0.f, 0.f};
    for (int mi = 0; mi < 4; ++mi)
        for (int ni = 0; ni < 4; ++ni) acc[mi][ni] = zero;

    const int srow = tid >> 3;          // manual staging
    const int sseg = (tid & 7) * 8;
    const int bkrow = tid >> 4;         // fp32 W staging
    const int bnseg = (tid & 15) * 8;
    const int arow = lane >> 3;         // async staging: 0..7
    const int akoff = ((lane & 7) * 8) ^ (arow * 8);   // swizzled source k
    const int sw = (l16 & 7) * 8;       // frag-read swizzle

    for (int k0 = 0; k0 < D_MODEL; k0 += 64) {
        __syncthreads();                // readers of previous tile done
        if (WT) {
            const __bf16* Ab = (const __bf16*)Ap;
            const __bf16* Bt = (const __bf16*)W;
            for (int it = 0; it < 4; ++it) {
                int row = wid * 32 + it * 8;   // wave-uniform LDS base
                ASYNC_CP16(&Ab[(size_t)(m0 + row + arow) * D_MODEL + k0 + akoff],
                           &As[row * 64]);
                ASYNC_CP16(&Bt[(size_t)(n0 + row + arow) * D_MODEL + k0 + akoff],
                           &Bs[row * 64]);
            }
        } else {
            if (MODE == 0) {
                const float* A = (const float*)Ap;
                for (int it = 0; it < 4; ++it) {
                    int row = srow + it * 32;
                    const float* src = &A[(size_t)(m0 + row) * D_MODEL + k0 + sseg];
                    float4 f0 = *(const float4*)src;
                    float4 f1 = *(const float4*)(src + 4);
                    union { uint4 u; __bf16 h[8]; } cv;
                    cv.h[0] = (__bf16)f0.x; cv.h[1] = (__bf16)f0.y;
                    cv.h[2] = (__bf16)f0.z; cv.h[3] = (__bf16)f0.w;
                    cv.h[4] = (__bf16)f1.x; cv.h[5] = (__bf16)f1.y;
                    cv.h[6] = (__bf16)f1.z; cv.h[7] = (__bf16)f1.w;
                    *(uint4*)&As[row * AST + sseg] = cv.u;
                }
            } else {
                const __bf16* A = (const __bf16*)Ap;
                for (int it = 0; it < 4; ++it) {
                    int row = srow + it * 32;
                    uint4 va = *(const uint4*)&A[(size_t)(m0 + row) * D_MODEL + k0 + sseg];
                    *(uint4*)&As[row * AST + sseg] = va;
                }
            }
            const float* Wf = (const float*)W;
            for (int it = 0; it < 4; ++it) {
                int krow = bkrow + it * 16;
                const float* src = &Wf[(size_t)(k0 + krow) * D_MODEL + n0 + bnseg];
                float4 f0 = *(const float4*)src;
                float4 f1 = *(const float4*)(src + 4);
                Bs[(bnseg + 0) * AST + krow] = (__bf16)f0.x;
                Bs[(bnseg + 1) * AST + krow] = (__bf16)f0.y;
                Bs[(bnseg + 2) * AST + krow] = (__bf16)f0.z;
                Bs[(bnseg + 3) * AST + krow] = (__bf16)f0.w;
                Bs[(bnseg + 4) * AST + krow] = (__bf16)f1.x;
                Bs[(bnseg + 5) * AST + krow] = (__bf16)f1.y;
                Bs[(bnseg + 6) * AST + krow] = (__bf16)f1.z;
                Bs[(bnseg + 7) * AST + krow] = (__bf16)f1.w;
            }
        }
        __syncthreads();                // drains vmcnt (async LDS) + lgkm
        for (int kk = 0; kk < 64; kk += 32) {
            bfrag af[4], bf[4];
            if (WT) {
                int ko = (kk + quad * 8) ^ sw;
                for (int mi = 0; mi < 4; ++mi)
                    af[mi] = *(const bfrag*)&As[(wRow + mi * 16 + l16) * 64 + ko];
                for (int ni = 0; ni < 4; ++ni)
                    bf[ni] = *(const bfrag*)&Bs[(wCol + ni * 16 + l16) * 64 + ko];
            } else {
                for (int mi = 0; mi < 4; ++mi)
                    af[mi] = *(const bfrag*)&As[(wRow + mi * 16 + l16) * AST + kk + quad * 8];
                for (int ni = 0; ni < 4; ++ni)
                    bf[ni] = *(const bfrag*)&Bs[(wCol + ni * 16 + l16) * AST + kk + quad * 8];
            }
            for (int mi = 0; mi < 4; ++mi)
                for (int ni = 0; ni < 4; ++ni)
                    acc[mi][ni] = MFMA(af[mi], bf[ni], acc[mi][ni]);
        }
    }

    for (int mi = 0; mi < 4; ++mi) {
        for (int ni = 0; ni < 4; ++ni) {
            int gn = n0 + wCol + ni * 16 + l16;
            float bv = bias[gn];
            if (MODE == 0) {
                int gm0 = m0 + wRow + mi * 16 + quad * 4;  // 4-aligned
                int b = gm0 >> 11, s0 = gm0 & 2047;
                int h = gn >> 6, d = gn & 63;
                if (z == 2) {
                    union { unsigned long long u; __bf16 h4[4]; } pk;
                    for (int r = 0; r < 4; ++r)
                        pk.h4[r] = (__bf16)(acc[mi][ni][r] + bv);
                    __bf16* dst = (__bf16*)dstp + (size_t)2 * (MROWS * (size_t)D_MODEL)
                                + ((((size_t)b * NH + h) * HD + d) * SEQ + s0);
                    *(unsigned long long*)dst = pk.u;
                } else {
                    __bf16* dst = (__bf16*)dstp + (size_t)z * (MROWS * (size_t)D_MODEL);
                    for (int r = 0; r < 4; ++r) {
                        float v = acc[mi][ni][r] + bv;
                        if (z == 0) v *= SCALE_LOG2;
                        dst[(((size_t)b * NH + h) * SEQ + s0 + r) * HD + d] = (__bf16)v;
                    }
                }
            } else {
                for (int r = 0; r < 4; ++r) {
                    int gm = m0 + wRow + mi * 16 + quad * 4 + r;
                    ((float*)dstp)[(size_t)gm * D_MODEL + gn] = acc[mi][ni][r] + bv;
                }
            }
        }
    }
}

// ---------------------------------------------------------------------------
// Flash attention (causal), S^T formulation, 128-row q-blocks.
// Block = (128 q-rows, head, batch); 4 waves, each owning 32 q-rows as two
// 16-row groups g=0,1. 64-key tiles; K/V staging+barriers amortized over 2x
// the q-rows of R6. Per-g sequential QK+softmax keeps VGPR pressure low.
// Q (pre-scaled) & K bf16 [b,h,s,d]; Vt bf16 [b,h,d,s]. LDS 36.9 KB -> 4/CU.
// ---------------------------------------------------------------------------
__global__ __launch_bounds__(256) void k_attn(
    const __bf16* __restrict__ Q, const __bf16* __restrict__ K,
    const __bf16* __restrict__ Vt, __bf16* __restrict__ O)
{
    alignas(16) __shared__ __bf16 Ks[64 * 72];
    alignas(16) __shared__ __bf16 Vts[64 * 72];    // [d][key]
    alignas(16) __shared__ __bf16 Ps[4][32 * 72];  // per-wave P^T: [qrow][key]

    const int tid = threadIdx.x, wid = tid >> 6, lane = tid & 63;
    const int quad = lane >> 4, l16 = lane & 15;
    const int qb = (blockIdx.x + blockIdx.y + 8 * blockIdx.z) & 15;
    const int h = blockIdx.y, b = blockIdx.z;
    const size_t bh = ((size_t)b * NH + h) * SEQ * HD;
    const __bf16* Qg  = Q + bh + (size_t)qb * 128 * HD;
    const __bf16* Kg  = K + bh;
    const __bf16* Vtg = Vt + ((size_t)b * NH + h) * HD * SEQ;  // [d][s]

    // Q fragments straight from global (per-lane contiguous 16 B)
    bfrag qf[2][2];
    for (int g = 0; g < 2; ++g) {
        const __bf16* qrow = &Qg[(size_t)(wid * 32 + g * 16 + l16) * HD];
        qf[g][0] = *(const bfrag*)&qrow[quad * 8];
        qf[g][1] = *(const bfrag*)&qrow[32 + quad * 8];
    }

    const f32x4 zero = {0.f, 0.f, 0.f, 0.f};
    f32x4 o[2][4];
    for (int g = 0; g < 2; ++g)
        for (int dt = 0; dt < 4; ++dt) o[g][dt] = zero;
    float mrow[2] = {NEG_BIG, NEG_BIG}, lrow[2] = {0.f, 0.f};
    int qv[2];
    for (int g = 0; g < 2; ++g) qv[g] = qb * 128 + wid * 32 + g * 16 + l16;
    const int srcbase = (lane & 48) + quad * 4;   // shfl src for C-row quad*4+r
    const int ntile = 2 * qb + 2;

    const int row0 = tid >> 3, seg = (tid & 7) * 8;

    // prefetch tile 0 into registers
    uint4 kreg0 = *(const uint4*)&Kg[(size_t)row0 * HD + seg];
    uint4 kreg1 = *(const uint4*)&Kg[(size_t)(row0 + 32) * HD + seg];
    uint4 vreg0 = *(const uint4*)&Vtg[(size_t)row0 * SEQ + seg];
    uint4 vreg1 = *(const uint4*)&Vtg[(size_t)(row0 + 32) * SEQ + seg];

    for (int t = 0; t < ntile; ++t) {
        const int j0 = t * 64;
        __syncthreads();   // all waves done reading previous tile's LDS
        *(uint4*)&Ks[row0 * 72 + seg] = kreg0;
        *(uint4*)&Ks[(row0 + 32) * 72 + seg] = kreg1;
        *(uint4*)&Vts[row0 * 72 + seg] = vreg0;
        *(uint4*)&Vts[(row0 + 32) * 72 + seg] = vreg1;
        if (t + 1 < ntile) {
            const int j1 = j0 + 64;
            kreg0 = *(const uint4*)&Kg[(size_t)(j1 + row0) * HD + seg];
            kreg1 = *(const uint4*)&Kg[(size_t)(j1 + row0 + 32) * HD + seg];
            vreg0 = *(const uint4*)&Vtg[(size_t)row0 * SEQ + j1 + seg];
            vreg1 = *(const uint4*)&Vtg[(size_t)(row0 + 32) * SEQ + j1 + seg];
        }
        __syncthreads();   // tile t LDS ready

        float alpha_s[2];
        for (int g = 0; g < 2; ++g) {
            // S^T: key = j0+kt*16+quad*4+r (C-row), qrow = qv[g] (C-col l16)
            f32x4 st[4];
            for (int kt = 0; kt < 4; ++kt) {
                bfrag ka0 = *(const bfrag*)&Ks[(kt * 16 + l16) * 72 + quad * 8];
                bfrag ka1 = *(const bfrag*)&Ks[(kt * 16 + l16) * 72 + 32 + quad * 8];
                st[kt] = MFMA(ka1, qf[g][1], MFMA(ka0, qf[g][0], zero));
            }
            // online softmax (scores in log2 domain; mask only last two tiles)
            float mloc = NEG_BIG;
            if (t >= ntile - 2) {
                for (int kt = 0; kt < 4; ++kt)
                    for (int r = 0; r < 4; ++r) {
                        float v = (j0 + kt * 16 + quad * 4 + r > qv[g]) ? NEG_BIG
                                                                        : st[kt][r];
                        st[kt][r] = v;
                        mloc = fmaxf(mloc, v);
                    }
            } else {
                for (int kt = 0; kt < 4; ++kt)
                    for (int r = 0; r < 4; ++r) mloc = fmaxf(mloc, st[kt][r]);
            }
            float m2 = fmaxf(mloc, __shfl_xor(mloc, 16, 64));
            m2 = fmaxf(m2, __shfl_xor(m2, 32, 64));
            float mnew = fmaxf(mrow[g], m2);
            alpha_s[g] = exp2f(mrow[g] - mnew);
            mrow[g] = mnew;
            float sloc = 0.f;
            for (int kt = 0; kt < 4; ++kt)
                for (int r = 0; r < 4; ++r) {
                    float p = exp2f(st[kt][r] - mnew);
                    st[kt][r] = p;
                    sloc += p;
                }
            float s2 = sloc + __shfl_xor(sloc, 16, 64);
            s2 = s2 + __shfl_xor(s2, 32, 64);
            lrow[g] = alpha_s[g] * lrow[g] + s2;

            // P^T -> Ps[wid][qrow][key]: 4 consecutive keys per b64 write
            for (int kt = 0; kt < 4; ++kt) {
                union { unsigned long long u; __bf16 h4[4]; } pk;
                for (int r = 0; r < 4; ++r) pk.h4[r] = (__bf16)st[kt][r];
                *(unsigned long long*)&Ps[wid][(g * 16 + l16) * 72 + kt * 16 + quad * 4]
                    = pk.u;
            }
        }
        asm volatile("s_waitcnt lgkmcnt(0)" ::: "memory");

        // rescale o (alpha per C-row gathered via shfl)
        for (int g = 0; g < 2; ++g)
            for (int r = 0; r < 4; ++r) {
                float ar = __shfl(alpha_s[g], srcbase + r, 64);
                for (int dt = 0; dt < 4; ++dt) o[g][dt][r] *= ar;
            }

        // O += P * V : A = Ps[qrow][key], B = Vts[d][key]; vf shared across g
        for (int c = 0; c < 2; ++c) {
            bfrag vf[4];
            for (int dt = 0; dt < 4; ++dt)
                vf[dt] = *(const bfrag*)&Vts[(dt * 16 + l16) * 72 + c * 32 + quad * 8];
            for (int g = 0; g < 2; ++g) {
                bfrag pf = *(const bfrag*)&Ps[wid][(g * 16 + l16) * 72 + c * 32 + quad * 8];
                for (int dt = 0; dt < 4; ++dt)
                    o[g][dt] = MFMA(pf, vf[dt], o[g][dt]);
            }
        }
    }

    // epilogue: normalize (lrow per C-row via shfl), write [B*S, D_MODEL]
    for (int g = 0; g < 2; ++g)
        for (int r = 0; r < 4; ++r) {
            float lr = __shfl(lrow[g], srcbase + r, 64);
            float inv = 1.0f / lr;
            size_t base = ((size_t)b * SEQ + qb * 128 + wid * 32 + g * 16
                           + quad * 4 + r) * D_MODEL + (size_t)h * HD;
            for (int dt = 0; dt < 4; ++dt)
                O[base + dt * 16 + l16] = (__bf16)(o[g][dt][r] * inv);
        }
}

// ---------------------------------------------------------------------------
extern "C" void kernel_launch(void* const* d_in, const int* in_sizes, int n_in,
                              void* d_out, int out_size, void* d_ws, size_t ws_size,
                              hipStream_t stream)
{
    const float* x  = (const float*)d_in[0];
    const float* Wq = (const float*)d_in[1];
    const float* bq = (const float*)d_in[2];
    const float* Wk = (const float*)d_in[3];
    const float* bk = (const float*)d_in[4];
    const float* Wv = (const float*)d_in[5];
    const float* bv = (const float*)d_in[6];
    const float* Wo = (const float*)d_in[7];
    const float* bo = (const float*)d_in[8];

    __bf16* ws = (__bf16*)d_ws;
    const size_t M1 = 1024u * 1024u;          // 1M elems
    __bf16* qkv    = ws;                      // Q @0, K @4M, Vt @8M (24 MB)
    __bf16* attn_o = ws + 12 * M1;            // 4M (8 MB)
    __bf16* Wt     = ws + 16 * M1;            // 4M bf16 transposed weights (8 MB)
    __bf16* xb     = ws + 20 * M1;            // 4M bf16 x (8 MB) -> 48 MB total

    const bool fast = ws_size >= (size_t)48 * 1024 * 1024;

    if (fast) {
        k_cvt_x<<<2048, 256, 0, stream>>>(x, xb);
        k_transpose4<<<dim3(16, 16, 4), 256, 0, stream>>>(Wq, Wk, Wv, Wo, Wt);
        k_gemm128<0, true><<<dim3(8, 32, 3), 256, 0, stream>>>(
            xb, Wt, Wt + M1, Wt + 2 * M1, bq, bk, bv, qkv);
        k_attn<<<dim3(16, 16, 2), 256, 0, stream>>>(
            qkv, qkv + 4 * M1, qkv + 8 * M1, attn_o);
        k_gemm128<1, true><<<dim3(8, 32, 1), 256, 0, stream>>>(
            attn_o, Wt + 3 * M1, Wt + 3 * M1, Wt + 3 * M1, bo, bo, bo, (float*)d_out);
    } else {
        k_gemm128<0, false><<<dim3(8, 32, 3), 256, 0, stream>>>(
            x, Wq, Wk, Wv, bq, bk, bv, qkv);
        k_attn<<<dim3(16, 16, 2), 256, 0, stream>>>(
            qkv, qkv + 4 * M1, qkv + 8 * M1, attn_o);
        k_gemm128<1, false><<<dim3(8, 32, 1), 256, 0, stream>>>(
            attn_o, Wo, Wo, Wo, bo, bo, bo, (float*)d_out);
    }
}

// Round 8
// 224.759 us; speedup vs baseline: 2.1033x; 1.0698x over previous
//
#include <hip/hip_runtime.h>

typedef __attribute__((ext_vector_type(8))) __bf16 bfrag;
typedef __attribute__((ext_vector_type(4))) float f32x4;

#define MFMA(a, b, c) __builtin_amdgcn_mfma_f32_16x16x32_bf16((a), (b), (c), 0, 0, 0)

#define D_MODEL 1024
#define SEQ     2048
#define NB      2
#define NH      16
#define HD      64
#define MROWS   (NB * SEQ)   // 4096

#define SCALE_LOG2 0.18033688011112043f   // log2(e)/sqrt(HD), folded into Q
#define NEG_BIG    (-3.0e38f)

#define GLOBAL_AS(p) ((const __attribute__((address_space(1))) void*)(p))
#define LDS_AS(p)    ((__attribute__((address_space(3))) void*)(p))
#define ASYNC_CP16(g, l) __builtin_amdgcn_global_load_lds(GLOBAL_AS(g), LDS_AS(l), 16, 0, 0)

// ---------------------------------------------------------------------------
// Prep: z<4 -> transpose weight z fp32 [K][N] -> bf16 [N][K]; z==4 -> x cvt.
// ---------------------------------------------------------------------------
__global__ __launch_bounds__(256) void k_prep(
    const float* __restrict__ x,
    const float* __restrict__ Wq, const float* __restrict__ Wk,
    const float* __restrict__ Wv, const float* __restrict__ Wo,
    __bf16* __restrict__ Wt, __bf16* __restrict__ xb)
{
    __shared__ __bf16 t[64][65];
    if (blockIdx.z == 4) {
        size_t base = ((size_t)(blockIdx.y * 16 + blockIdx.x)) * 16384;
        for (int j = 0; j < 8; ++j) {
            size_t i = base + (size_t)j * 2048 + (size_t)threadIdx.x * 8;
            float4 f0 = *(const float4*)&x[i];
            float4 f1 = *(const float4*)&x[i + 4];
            union { uint4 u; __bf16 h[8]; } cv;
            cv.h[0] = (__bf16)f0.x; cv.h[1] = (__bf16)f0.y;
            cv.h[2] = (__bf16)f0.z; cv.h[3] = (__bf16)f0.w;
            cv.h[4] = (__bf16)f1.x; cv.h[5] = (__bf16)f1.y;
            cv.h[6] = (__bf16)f1.z; cv.h[7] = (__bf16)f1.w;
            *(uint4*)&xb[i] = cv.u;
        }
        return;
    }
    const float* src = (blockIdx.z == 0) ? Wq : (blockIdx.z == 1) ? Wk
                      : (blockIdx.z == 2) ? Wv : Wo;
    __bf16* dst = Wt + (size_t)blockIdx.z * (1024u * 1024u);
    int tr = blockIdx.y * 64, tc = blockIdx.x * 64;
    for (int j = 0; j < 16; ++j) {
        int id = threadIdx.x + j * 256;
        int r = id >> 6, c = id & 63;
        t[r][c] = (__bf16)src[(size_t)(tr + r) * 1024 + tc + c];
    }
    __syncthreads();
    for (int j = 0; j < 16; ++j) {
        int id = threadIdx.x + j * 256;
        int r = id >> 6, c = id & 63;
        dst[(size_t)(tc + r) * 1024 + tr + c] = t[c][r];
    }
}

// ---------------------------------------------------------------------------
// GEMM: Y[4096][1024] = A * W + bias (bf16 MFMA).
// WT=true : A bf16, W bf16 [n][k]; global_load_lds w16 staging, XOR-swizzled
//           unpadded LDS (R7, verified). WT=false: fp32 fallback staging.
// MODE 0 epilogue: C restaged through LDS (stride 136) for coalesced 16-B
//   stores. z=0 -> Q [b,h,s,d] (pre-scaled); z=1 -> K; z=2 -> V [b,h,d,s].
// MODE 1: fp32 row-major direct (64-B line segments, OK).
// ---------------------------------------------------------------------------
template <int MODE, bool WT>
__global__ __launch_bounds__(256) void k_gemm128(
    const void* __restrict__ Ap,
    const void* __restrict__ W0, const void* __restrict__ W1,
    const void* __restrict__ W2,
    const float* __restrict__ b0, const float* __restrict__ b1,
    const float* __restrict__ b2, void* __restrict__ dstp)
{
    constexpr int AST = WT ? 64 : 72;
    alignas(16) __shared__ __bf16 SH[18432];   // 36 KB: staging + C restage
    __bf16* As = SH;
    __bf16* Bs = SH + 128 * AST;

    const int tid = threadIdx.x;
    const int z = blockIdx.z;
    const int m0 = blockIdx.y * 128;
    const int n0 = blockIdx.x * 128;
    const void* W     = (z == 0) ? W0 : (z == 1) ? W1 : W2;
    const float* bias = (z == 0) ? b0 : (z == 1) ? b1 : b2;

    const int wid = tid >> 6, lane = tid & 63;
    const int quad = lane >> 4, l16 = lane & 15;
    const int wRow = (wid >> 1) * 64, wCol = (wid & 1) * 64;

    f32x4 acc[4][4];
    const f32x4 zero = {0.f, 0.f, 0.f, 0.f};
    for (int mi = 0; mi < 4; ++mi)
        for (int ni = 0; ni < 4; ++ni) acc[mi][ni] = zero;

    const int srow = tid >> 3;
    const int sseg = (tid & 7) * 8;
    const int bkrow = tid >> 4;
    const int bnseg = (tid & 15) * 8;
    const int arow = lane >> 3;                        // async staging
    const int akoff = ((lane & 7) * 8) ^ (arow * 8);   // swizzled source k
    const int sw = (l16 & 7) * 8;                      // frag-read swizzle

    for (int k0 = 0; k0 < D_MODEL; k0 += 64) {
        __syncthreads();
        if (WT) {
            const __bf16* Ab = (const __bf16*)Ap;
            const __bf16* Bt = (const __bf16*)W;
            for (int it = 0; it < 4; ++it) {
                int row = wid * 32 + it * 8;
                ASYNC_CP16(&Ab[(size_t)(m0 + row + arow) * D_MODEL + k0 + akoff],
                           &As[row * 64]);
                ASYNC_CP16(&Bt[(size_t)(n0 + row + arow) * D_MODEL + k0 + akoff],
                           &Bs[row * 64]);
            }
        } else {
            if (MODE == 0) {
                const float* A = (const float*)Ap;
                for (int it = 0; it < 4; ++it) {
                    int row = srow + it * 32;
                    const float* src = &A[(size_t)(m0 + row) * D_MODEL + k0 + sseg];
                    float4 f0 = *(const float4*)src;
                    float4 f1 = *(const float4*)(src + 4);
                    union { uint4 u; __bf16 h[8]; } cv;
                    cv.h[0] = (__bf16)f0.x; cv.h[1] = (__bf16)f0.y;
                    cv.h[2] = (__bf16)f0.z; cv.h[3] = (__bf16)f0.w;
                    cv.h[4] = (__bf16)f1.x; cv.h[5] = (__bf16)f1.y;
                    cv.h[6] = (__bf16)f1.z; cv.h[7] = (__bf16)f1.w;
                    *(uint4*)&As[row * AST + sseg] = cv.u;
                }
            } else {
                const __bf16* A = (const __bf16*)Ap;
                for (int it = 0; it < 4; ++it) {
                    int row = srow + it * 32;
                    uint4 va = *(const uint4*)&A[(size_t)(m0 + row) * D_MODEL + k0 + sseg];
                    *(uint4*)&As[row * AST + sseg] = va;
                }
            }
            const float* Wf = (const float*)W;
            for (int it = 0; it < 4; ++it) {
                int krow = bkrow + it * 16;
                const float* src = &Wf[(size_t)(k0 + krow) * D_MODEL + n0 + bnseg];
                float4 f0 = *(const float4*)src;
                float4 f1 = *(const float4*)(src + 4);
                Bs[(bnseg + 0) * AST + krow] = (__bf16)f0.x;
                Bs[(bnseg + 1) * AST + krow] = (__bf16)f0.y;
                Bs[(bnseg + 2) * AST + krow] = (__bf16)f0.z;
                Bs[(bnseg + 3) * AST + krow] = (__bf16)f0.w;
                Bs[(bnseg + 4) * AST + krow] = (__bf16)f1.x;
                Bs[(bnseg + 5) * AST + krow] = (__bf16)f1.y;
                Bs[(bnseg + 6) * AST + krow] = (__bf16)f1.z;
                Bs[(bnseg + 7) * AST + krow] = (__bf16)f1.w;
            }
        }
        __syncthreads();
        for (int kk = 0; kk < 64; kk += 32) {
            bfrag af[4], bf[4];
            if (WT) {
                int ko = (kk + quad * 8) ^ sw;
                for (int mi = 0; mi < 4; ++mi)
                    af[mi] = *(const bfrag*)&As[(wRow + mi * 16 + l16) * 64 + ko];
                for (int ni = 0; ni < 4; ++ni)
                    bf[ni] = *(const bfrag*)&Bs[(wCol + ni * 16 + l16) * 64 + ko];
            } else {
                for (int mi = 0; mi < 4; ++mi)
                    af[mi] = *(const bfrag*)&As[(wRow + mi * 16 + l16) * AST + kk + quad * 8];
                for (int ni = 0; ni < 4; ++ni)
                    bf[ni] = *(const bfrag*)&Bs[(wCol + ni * 16 + l16) * AST + kk + quad * 8];
            }
            for (int mi = 0; mi < 4; ++mi)
                for (int ni = 0; ni < 4; ++ni)
                    acc[mi][ni] = MFMA(af[mi], bf[ni], acc[mi][ni]);
        }
    }

    if (MODE == 0) {
        float biasv[4];
        for (int ni = 0; ni < 4; ++ni) biasv[ni] = bias[n0 + wCol + ni * 16 + l16];
        const int b = m0 >> 11, m0s = m0 & 2047, h0 = n0 >> 6;
        __syncthreads();   // all waves done with As/Bs before reuse as C-stage
        if (z < 2) {
            // CS[s][col] , col = hl*64 + d ; stride 136 (272 B, 16-B aligned)
            for (int mi = 0; mi < 4; ++mi)
                for (int ni = 0; ni < 4; ++ni) {
                    int col = wCol + ni * 16 + l16;
                    for (int r = 0; r < 4; ++r) {
                        float v = acc[mi][ni][r] + biasv[ni];
                        if (z == 0) v *= SCALE_LOG2;
                        SH[(wRow + mi * 16 + quad * 4 + r) * 136 + col] = (__bf16)v;
                    }
                }
            __syncthreads();
            __bf16* qk = (__bf16*)dstp + (size_t)z * (MROWS * (size_t)D_MODEL);
            for (int i = 0; i < 8; ++i) {
                int rid = i * 32 + (tid >> 3);        // 0..255 = (hl, s_local)
                int hl = rid >> 7, sl = rid & 127;
                int dcol = (tid & 7) * 8;
                uint4 v = *(const uint4*)&SH[sl * 136 + hl * 64 + dcol];
                *(uint4*)&qk[(((size_t)b * NH + h0 + hl) * SEQ + m0s + sl) * HD + dcol] = v;
            }
        } else {
            // CS[col][s] , col = hl*64 + d ; stride 136
            for (int mi = 0; mi < 4; ++mi)
                for (int ni = 0; ni < 4; ++ni) {
                    int col = wCol + ni * 16 + l16;
                    int s0 = wRow + mi * 16 + quad * 4;
                    union { unsigned long long u; __bf16 h4[4]; } pk;
                    for (int r = 0; r < 4; ++r)
                        pk.h4[r] = (__bf16)(acc[mi][ni][r] + biasv[ni]);
                    *(unsigned long long*)&SH[col * 136 + s0] = pk.u;
                }
            __syncthreads();
            __bf16* vv = (__bf16*)dstp + (size_t)2 * (MROWS * (size_t)D_MODEL);
            for (int i = 0; i < 8; ++i) {
                int rid = i * 16 + (tid >> 4);        // 0..127 = (hl, d)
                int hl = rid >> 6, d = rid & 63;
                int sc = (tid & 15) * 8;
                uint4 v = *(const uint4*)&SH[rid * 136 + sc];
                *(uint4*)&vv[(((size_t)b * NH + h0 + hl) * HD + d) * SEQ + m0s + sc] = v;
            }
        }
    } else {
        for (int mi = 0; mi < 4; ++mi)
            for (int ni = 0; ni < 4; ++ni) {
                int gn = n0 + wCol + ni * 16 + l16;
                float bv = bias[gn];
                for (int r = 0; r < 4; ++r) {
                    int gm = m0 + wRow + mi * 16 + quad * 4 + r;
                    ((float*)dstp)[(size_t)gm * D_MODEL + gn] = acc[mi][ni][r] + bv;
                }
            }
    }
}

// ---------------------------------------------------------------------------
// Flash attention (causal), S^T formulation (R6 config: 64-row q-blocks,
// 1024 blocks, 5 blocks/CU) + critical-path reorder: lrow sum-shuffles moved
// after PV MFMA issue; alpha-gather before the lgkm wait.
// ---------------------------------------------------------------------------
__global__ __launch_bounds__(256) void k_attn(
    const __bf16* __restrict__ Q, const __bf16* __restrict__ K,
    const __bf16* __restrict__ Vt, __bf16* __restrict__ O)
{
    alignas(16) __shared__ __bf16 Ks[64 * 72];
    alignas(16) __shared__ __bf16 Vts[64 * 72];    // [d][key]
    alignas(16) __shared__ __bf16 Ps[4][16 * 72];  // per-wave P^T: [qrow][key]

    const int tid = threadIdx.x, wid = tid >> 6, lane = tid & 63;
    const int quad = lane >> 4, l16 = lane & 15;
    const int qb = (blockIdx.x + blockIdx.y + 16 * blockIdx.z) & 31;
    const int h = blockIdx.y, b = blockIdx.z;
    const size_t bh = ((size_t)b * NH + h) * SEQ * HD;
    const __bf16* Qg  = Q + bh + (size_t)qb * 64 * HD;
    const __bf16* Kg  = K + bh;
    const __bf16* Vtg = Vt + ((size_t)b * NH + h) * HD * SEQ;  // [d][s]

    bfrag qf[2];
    qf[0] = *(const bfrag*)&Qg[(size_t)(wid * 16 + l16) * HD + quad * 8];
    qf[1] = *(const bfrag*)&Qg[(size_t)(wid * 16 + l16) * HD + 32 + quad * 8];

    const f32x4 zero = {0.f, 0.f, 0.f, 0.f};
    f32x4 o[4];
    for (int dt = 0; dt < 4; ++dt) o[dt] = zero;
    float mrow = NEG_BIG, lrow = 0.f;
    const int q = qb * 64 + wid * 16 + l16;
    const int srcbase = (lane & 48) + quad * 4;
    const int ntile = qb + 1;

    const int row0 = tid >> 3, seg = (tid & 7) * 8;

    uint4 kreg0 = *(const uint4*)&Kg[(size_t)row0 * HD + seg];
    uint4 kreg1 = *(const uint4*)&Kg[(size_t)(row0 + 32) * HD + seg];
    uint4 vreg0 = *(const uint4*)&Vtg[(size_t)row0 * SEQ + seg];
    uint4 vreg1 = *(const uint4*)&Vtg[(size_t)(row0 + 32) * SEQ + seg];

    for (int t = 0; t < ntile; ++t) {
        const int j0 = t * 64;
        __syncthreads();
        *(uint4*)&Ks[row0 * 72 + seg] = kreg0;
        *(uint4*)&Ks[(row0 + 32) * 72 + seg] = kreg1;
        *(uint4*)&Vts[row0 * 72 + seg] = vreg0;
        *(uint4*)&Vts[(row0 + 32) * 72 + seg] = vreg1;
        if (t + 1 < ntile) {
            const int j1 = j0 + 64;
            kreg0 = *(const uint4*)&Kg[(size_t)(j1 + row0) * HD + seg];
            kreg1 = *(const uint4*)&Kg[(size_t)(j1 + row0 + 32) * HD + seg];
            vreg0 = *(const uint4*)&Vtg[(size_t)row0 * SEQ + j1 + seg];
            vreg1 = *(const uint4*)&Vtg[(size_t)(row0 + 32) * SEQ + j1 + seg];
        }
        __syncthreads();

        f32x4 st[4];
        for (int kt = 0; kt < 4; ++kt) {
            bfrag ka0 = *(const bfrag*)&Ks[(kt * 16 + l16) * 72 + quad * 8];
            bfrag ka1 = *(const bfrag*)&Ks[(kt * 16 + l16) * 72 + 32 + quad * 8];
            st[kt] = MFMA(ka1, qf[1], MFMA(ka0, qf[0], zero));
        }

        float mloc = NEG_BIG;
        if (t == ntile - 1) {
            for (int kt = 0; kt < 4; ++kt)
                for (int r = 0; r < 4; ++r) {
                    float v = (j0 + kt * 16 + quad * 4 + r > q) ? NEG_BIG : st[kt][r];
                    st[kt][r] = v;
                    mloc = fmaxf(mloc, v);
                }
        } else {
            for (int kt = 0; kt < 4; ++kt)
                for (int r = 0; r < 4; ++r) mloc = fmaxf(mloc, st[kt][r]);
        }
        float m2 = fmaxf(mloc, __shfl_xor(mloc, 16, 64));
        m2 = fmaxf(m2, __shfl_xor(m2, 32, 64));
        float mnew = fmaxf(mrow, m2);
        float alpha = exp2f(mrow - mnew);
        mrow = mnew;
        float sloc = 0.f;
        for (int kt = 0; kt < 4; ++kt)
            for (int r = 0; r < 4; ++r) {
                float p = exp2f(st[kt][r] - mnew);
                st[kt][r] = p;
                sloc += p;
            }

        // P^T writes first (feeds PV), bookkeeping overlapped after
        for (int kt = 0; kt < 4; ++kt) {
            union { unsigned long long u; __bf16 h4[4]; } pk;
            for (int r = 0; r < 4; ++r) pk.h4[r] = (__bf16)st[kt][r];
            *(unsigned long long*)&Ps[wid][l16 * 72 + kt * 16 + quad * 4] = pk.u;
        }

        // rescale o (independent of Ps)
        for (int r = 0; r < 4; ++r) {
            float ar = __shfl(alpha, srcbase + r, 64);
            for (int dt = 0; dt < 4; ++dt) o[dt][r] *= ar;
        }
        asm volatile("s_waitcnt lgkmcnt(0)" ::: "memory");

        for (int c = 0; c < 2; ++c) {
            bfrag pf = *(const bfrag*)&Ps[wid][l16 * 72 + c * 32 + quad * 8];
            for (int dt = 0; dt < 4; ++dt) {
                bfrag vf = *(const bfrag*)&Vts[(dt * 16 + l16) * 72 + c * 32 + quad * 8];
                o[dt] = MFMA(pf, vf, o[dt]);
            }
        }

        // lrow update overlaps PV MFMA latency
        float s2 = sloc + __shfl_xor(sloc, 16, 64);
        s2 = s2 + __shfl_xor(s2, 32, 64);
        lrow = alpha * lrow + s2;
    }

    for (int r = 0; r < 4; ++r) {
        float lr = __shfl(lrow, srcbase + r, 64);
        float inv = 1.0f / lr;
        size_t base = ((size_t)b * SEQ + qb * 64 + wid * 16 + quad * 4 + r) * D_MODEL
                    + (size_t)h * HD;
        for (int dt = 0; dt < 4; ++dt)
            O[base + dt * 16 + l16] = (__bf16)(o[dt][r] * inv);
    }
}

// ---------------------------------------------------------------------------
extern "C" void kernel_launch(void* const* d_in, const int* in_sizes, int n_in,
                              void* d_out, int out_size, void* d_ws, size_t ws_size,
                              hipStream_t stream)
{
    const float* x  = (const float*)d_in[0];
    const float* Wq = (const float*)d_in[1];
    const float* bq = (const float*)d_in[2];
    const float* Wk = (const float*)d_in[3];
    const float* bk = (const float*)d_in[4];
    const float* Wv = (const float*)d_in[5];
    const float* bv = (const float*)d_in[6];
    const float* Wo = (const float*)d_in[7];
    const float* bo = (const float*)d_in[8];

    __bf16* ws = (__bf16*)d_ws;
    const size_t M1 = 1024u * 1024u;
    __bf16* qkv    = ws;                      // Q @0, K @4M, Vt @8M (24 MB)
    __bf16* attn_o = ws + 12 * M1;            // 4M (8 MB)
    __bf16* Wt     = ws + 16 * M1;            // 4M (8 MB)
    __bf16* xb     = ws + 20 * M1;            // 4M (8 MB) -> 48 MB total

    const bool fast = ws_size >= (size_t)48 * 1024 * 1024;

    if (fast) {
        k_prep<<<dim3(16, 16, 5), 256, 0, stream>>>(x, Wq, Wk, Wv, Wo, Wt, xb);
        k_gemm128<0, true><<<dim3(8, 32, 3), 256, 0, stream>>>(
            xb, Wt, Wt + M1, Wt + 2 * M1, bq, bk, bv, qkv);
        k_attn<<<dim3(32, 16, 2), 256, 0, stream>>>(
            qkv, qkv + 4 * M1, qkv + 8 * M1, attn_o);
        k_gemm128<1, true><<<dim3(8, 32, 1), 256, 0, stream>>>(
            attn_o, Wt + 3 * M1, Wt + 3 * M1, Wt + 3 * M1, bo, bo, bo, (float*)d_out);
    } else {
        k_gemm128<0, false><<<dim3(8, 32, 3), 256, 0, stream>>>(
            x, Wq, Wk, Wv, bq, bk, bv, qkv);
        k_attn<<<dim3(32, 16, 2), 256, 0, stream>>>(
            qkv, qkv + 4 * M1, qkv + 8 * M1, attn_o);
        k_gemm128<1, false><<<dim3(8, 32, 1), 256, 0, stream>>>(
            attn_o, Wo, Wo, Wo, bo, bo, bo, (float*)d_out);
    }
}

// Round 9
// 212.469 us; speedup vs baseline: 2.2250x; 1.0578x over previous
//
#include <hip/hip_runtime.h>

typedef __attribute__((ext_vector_type(8))) __bf16 bfrag;
typedef __attribute__((ext_vector_type(4))) float f32x4;

#define MFMA(a, b, c) __builtin_amdgcn_mfma_f32_16x16x32_bf16((a), (b), (c), 0, 0, 0)

#define D_MODEL 1024
#define SEQ     2048
#define NB      2
#define NH      16
#define HD      64
#define MROWS   (NB * SEQ)   // 4096

#define SCALE_LOG2 0.18033688011112043f   // log2(e)/sqrt(HD), folded into Q
#define NEG_BIG    (-3.0e38f)

#define GLOBAL_AS(p) ((const __attribute__((address_space(1))) void*)(p))
#define LDS_AS(p)    ((__attribute__((address_space(3))) void*)(p))
#define ASYNC_CP16(g, l) __builtin_amdgcn_global_load_lds(GLOBAL_AS(g), LDS_AS(l), 16, 0, 0)

// ---------------------------------------------------------------------------
// Prep: z<4 -> transpose weight z fp32 [K][N] -> bf16 [N][K]; z==4 -> x cvt.
// ---------------------------------------------------------------------------
__global__ __launch_bounds__(256) void k_prep(
    const float* __restrict__ x,
    const float* __restrict__ Wq, const float* __restrict__ Wk,
    const float* __restrict__ Wv, const float* __restrict__ Wo,
    __bf16* __restrict__ Wt, __bf16* __restrict__ xb)
{
    __shared__ __bf16 t[64][65];
    if (blockIdx.z == 4) {
        size_t base = ((size_t)(blockIdx.y * 16 + blockIdx.x)) * 16384;
        for (int j = 0; j < 8; ++j) {
            size_t i = base + (size_t)j * 2048 + (size_t)threadIdx.x * 8;
            float4 f0 = *(const float4*)&x[i];
            float4 f1 = *(const float4*)&x[i + 4];
            union { uint4 u; __bf16 h[8]; } cv;
            cv.h[0] = (__bf16)f0.x; cv.h[1] = (__bf16)f0.y;
            cv.h[2] = (__bf16)f0.z; cv.h[3] = (__bf16)f0.w;
            cv.h[4] = (__bf16)f1.x; cv.h[5] = (__bf16)f1.y;
            cv.h[6] = (__bf16)f1.z; cv.h[7] = (__bf16)f1.w;
            *(uint4*)&xb[i] = cv.u;
        }
        return;
    }
    const float* src = (blockIdx.z == 0) ? Wq : (blockIdx.z == 1) ? Wk
                      : (blockIdx.z == 2) ? Wv : Wo;
    __bf16* dst = Wt + (size_t)blockIdx.z * (1024u * 1024u);
    int tr = blockIdx.y * 64, tc = blockIdx.x * 64;
    for (int j = 0; j < 16; ++j) {
        int id = threadIdx.x + j * 256;
        int r = id >> 6, c = id & 63;
        t[r][c] = (__bf16)src[(size_t)(tr + r) * 1024 + tc + c];
    }
    __syncthreads();
    for (int j = 0; j < 16; ++j) {
        int id = threadIdx.x + j * 256;
        int r = id >> 6, c = id & 63;
        dst[(size_t)(tc + r) * 1024 + tr + c] = t[c][r];
    }
}

// ---------------------------------------------------------------------------
// QKV GEMM (and fp32-fallback GEMM): Y[4096][1024] = A * W + bias.
// Same as R8 (verified): WT=true async+swizzled; WT=false fp32 staging.
// MODE 0 epilogue: LDS-restaged coalesced stores (Q/K [b,h,s,d], V [b,h,d,s]).
// MODE 1 (fallback only): fp32 row-major direct.
// ---------------------------------------------------------------------------
template <int MODE, bool WT>
__global__ __launch_bounds__(256) void k_gemm128(
    const void* __restrict__ Ap,
    const void* __restrict__ W0, const void* __restrict__ W1,
    const void* __restrict__ W2,
    const float* __restrict__ b0, const float* __restrict__ b1,
    const float* __restrict__ b2, void* __restrict__ dstp)
{
    constexpr int AST = WT ? 64 : 72;
    alignas(16) __shared__ __bf16 SH[18432];   // 36 KB: staging + C restage
    __bf16* As = SH;
    __bf16* Bs = SH + 128 * AST;

    const int tid = threadIdx.x;
    const int z = blockIdx.z;
    const int m0 = blockIdx.y * 128;
    const int n0 = blockIdx.x * 128;
    const void* W     = (z == 0) ? W0 : (z == 1) ? W1 : W2;
    const float* bias = (z == 0) ? b0 : (z == 1) ? b1 : b2;

    const int wid = tid >> 6, lane = tid & 63;
    const int quad = lane >> 4, l16 = lane & 15;
    const int wRow = (wid >> 1) * 64, wCol = (wid & 1) * 64;

    f32x4 acc[4][4];
    const f32x4 zero = {0.f, 0.f, 0.f, 0.f};
    for (int mi = 0; mi < 4; ++mi)
        for (int ni = 0; ni < 4; ++ni) acc[mi][ni] = zero;

    const int srow = tid >> 3;
    const int sseg = (tid & 7) * 8;
    const int bkrow = tid >> 4;
    const int bnseg = (tid & 15) * 8;
    const int arow = lane >> 3;
    const int akoff = ((lane & 7) * 8) ^ (arow * 8);
    const int sw = (l16 & 7) * 8;

    for (int k0 = 0; k0 < D_MODEL; k0 += 64) {
        __syncthreads();
        if (WT) {
            const __bf16* Ab = (const __bf16*)Ap;
            const __bf16* Bt = (const __bf16*)W;
            for (int it = 0; it < 4; ++it) {
                int row = wid * 32 + it * 8;
                ASYNC_CP16(&Ab[(size_t)(m0 + row + arow) * D_MODEL + k0 + akoff],
                           &As[row * 64]);
                ASYNC_CP16(&Bt[(size_t)(n0 + row + arow) * D_MODEL + k0 + akoff],
                           &Bs[row * 64]);
            }
        } else {
            if (MODE == 0) {
                const float* A = (const float*)Ap;
                for (int it = 0; it < 4; ++it) {
                    int row = srow + it * 32;
                    const float* src = &A[(size_t)(m0 + row) * D_MODEL + k0 + sseg];
                    float4 f0 = *(const float4*)src;
                    float4 f1 = *(const float4*)(src + 4);
                    union { uint4 u; __bf16 h[8]; } cv;
                    cv.h[0] = (__bf16)f0.x; cv.h[1] = (__bf16)f0.y;
                    cv.h[2] = (__bf16)f0.z; cv.h[3] = (__bf16)f0.w;
                    cv.h[4] = (__bf16)f1.x; cv.h[5] = (__bf16)f1.y;
                    cv.h[6] = (__bf16)f1.z; cv.h[7] = (__bf16)f1.w;
                    *(uint4*)&As[row * AST + sseg] = cv.u;
                }
            } else {
                const __bf16* A = (const __bf16*)Ap;
                for (int it = 0; it < 4; ++it) {
                    int row = srow + it * 32;
                    uint4 va = *(const uint4*)&A[(size_t)(m0 + row) * D_MODEL + k0 + sseg];
                    *(uint4*)&As[row * AST + sseg] = va;
                }
            }
            const float* Wf = (const float*)W;
            for (int it = 0; it < 4; ++it) {
                int krow = bkrow + it * 16;
                const float* src = &Wf[(size_t)(k0 + krow) * D_MODEL + n0 + bnseg];
                float4 f0 = *(const float4*)src;
                float4 f1 = *(const float4*)(src + 4);
                Bs[(bnseg + 0) * AST + krow] = (__bf16)f0.x;
                Bs[(bnseg + 1) * AST + krow] = (__bf16)f0.y;
                Bs[(bnseg + 2) * AST + krow] = (__bf16)f0.z;
                Bs[(bnseg + 3) * AST + krow] = (__bf16)f0.w;
                Bs[(bnseg + 4) * AST + krow] = (__bf16)f1.x;
                Bs[(bnseg + 5) * AST + krow] = (__bf16)f1.y;
                Bs[(bnseg + 6) * AST + krow] = (__bf16)f1.z;
                Bs[(bnseg + 7) * AST + krow] = (__bf16)f1.w;
            }
        }
        __syncthreads();
        for (int kk = 0; kk < 64; kk += 32) {
            bfrag af[4], bf[4];
            if (WT) {
                int ko = (kk + quad * 8) ^ sw;
                for (int mi = 0; mi < 4; ++mi)
                    af[mi] = *(const bfrag*)&As[(wRow + mi * 16 + l16) * 64 + ko];
                for (int ni = 0; ni < 4; ++ni)
                    bf[ni] = *(const bfrag*)&Bs[(wCol + ni * 16 + l16) * 64 + ko];
            } else {
                for (int mi = 0; mi < 4; ++mi)
                    af[mi] = *(const bfrag*)&As[(wRow + mi * 16 + l16) * AST + kk + quad * 8];
                for (int ni = 0; ni < 4; ++ni)
                    bf[ni] = *(const bfrag*)&Bs[(wCol + ni * 16 + l16) * AST + kk + quad * 8];
            }
            for (int mi = 0; mi < 4; ++mi)
                for (int ni = 0; ni < 4; ++ni)
                    acc[mi][ni] = MFMA(af[mi], bf[ni], acc[mi][ni]);
        }
    }

    if (MODE == 0) {
        float biasv[4];
        for (int ni = 0; ni < 4; ++ni) biasv[ni] = bias[n0 + wCol + ni * 16 + l16];
        const int b = m0 >> 11, m0s = m0 & 2047, h0 = n0 >> 6;
        __syncthreads();
        if (z < 2) {
            for (int mi = 0; mi < 4; ++mi)
                for (int ni = 0; ni < 4; ++ni) {
                    int col = wCol + ni * 16 + l16;
                    for (int r = 0; r < 4; ++r) {
                        float v = acc[mi][ni][r] + biasv[ni];
                        if (z == 0) v *= SCALE_LOG2;
                        SH[(wRow + mi * 16 + quad * 4 + r) * 136 + col] = (__bf16)v;
                    }
                }
            __syncthreads();
            __bf16* qk = (__bf16*)dstp + (size_t)z * (MROWS * (size_t)D_MODEL);
            for (int i = 0; i < 8; ++i) {
                int rid = i * 32 + (tid >> 3);
                int hl = rid >> 7, sl = rid & 127;
                int dcol = (tid & 7) * 8;
                uint4 v = *(const uint4*)&SH[sl * 136 + hl * 64 + dcol];
                *(uint4*)&qk[(((size_t)b * NH + h0 + hl) * SEQ + m0s + sl) * HD + dcol] = v;
            }
        } else {
            for (int mi = 0; mi < 4; ++mi)
                for (int ni = 0; ni < 4; ++ni) {
                    int col = wCol + ni * 16 + l16;
                    int s0 = wRow + mi * 16 + quad * 4;
                    union { unsigned long long u; __bf16 h4[4]; } pk;
                    for (int r = 0; r < 4; ++r)
                        pk.h4[r] = (__bf16)(acc[mi][ni][r] + biasv[ni]);
                    *(unsigned long long*)&SH[col * 136 + s0] = pk.u;
                }
            __syncthreads();
            __bf16* vv = (__bf16*)dstp + (size_t)2 * (MROWS * (size_t)D_MODEL);
            for (int i = 0; i < 8; ++i) {
                int rid = i * 16 + (tid >> 4);
                int hl = rid >> 6, d = rid & 63;
                int sc = (tid & 15) * 8;
                uint4 v = *(const uint4*)&SH[rid * 136 + sc];
                *(uint4*)&vv[(((size_t)b * NH + h0 + hl) * HD + d) * SEQ + m0s + sc] = v;
            }
        }
    } else {
        for (int mi = 0; mi < 4; ++mi)
            for (int ni = 0; ni < 4; ++ni) {
                int gn = n0 + wCol + ni * 16 + l16;
                float bv = bias[gn];
                for (int r = 0; r < 4; ++r) {
                    int gm = m0 + wRow + mi * 16 + quad * 4 + r;
                    ((float*)dstp)[(size_t)gm * D_MODEL + gn] = acc[mi][ni][r] + bv;
                }
            }
    }
}

// ---------------------------------------------------------------------------
// Output GEMM (fast path): Y[4096][1024] fp32 = A(bf16) * WoT(bf16 [n][k]) + bo.
// 64(M)x128(N) tiles -> grid 512 (2 blocks/CU). Async+swizzled staging.
// Wave tile 32x64: wRow=(wid>>1)*32, wCol=(wid&1)*64, acc[2][4].
// ---------------------------------------------------------------------------
__global__ __launch_bounds__(256) void k_gemm_out(
    const __bf16* __restrict__ A, const __bf16* __restrict__ Bt,
    const float* __restrict__ bias, float* __restrict__ dst)
{
    alignas(16) __shared__ __bf16 As[64 * 64];    // 8 KB
    alignas(16) __shared__ __bf16 Bs[128 * 64];   // 16 KB

    const int tid = threadIdx.x;
    const int m0 = blockIdx.y * 64;
    const int n0 = blockIdx.x * 128;
    const int wid = tid >> 6, lane = tid & 63;
    const int quad = lane >> 4, l16 = lane & 15;
    const int wRow = (wid >> 1) * 32, wCol = (wid & 1) * 64;

    f32x4 acc[2][4];
    const f32x4 zero = {0.f, 0.f, 0.f, 0.f};
    for (int mi = 0; mi < 2; ++mi)
        for (int ni = 0; ni < 4; ++ni) acc[mi][ni] = zero;

    const int arow = lane >> 3;
    const int akoff = ((lane & 7) * 8) ^ (arow * 8);
    const int sw = (l16 & 7) * 8;

    for (int k0 = 0; k0 < D_MODEL; k0 += 64) {
        __syncthreads();
        for (int it = 0; it < 2; ++it) {
            int row = wid * 16 + it * 8;
            ASYNC_CP16(&A[(size_t)(m0 + row + arow) * D_MODEL + k0 + akoff],
                       &As[row * 64]);
        }
        for (int it = 0; it < 4; ++it) {
            int row = wid * 32 + it * 8;
            ASYNC_CP16(&Bt[(size_t)(n0 + row + arow) * D_MODEL + k0 + akoff],
                       &Bs[row * 64]);
        }
        __syncthreads();
        for (int kk = 0; kk < 64; kk += 32) {
            int ko = (kk + quad * 8) ^ sw;
            bfrag af[2], bf[4];
            for (int mi = 0; mi < 2; ++mi)
                af[mi] = *(const bfrag*)&As[(wRow + mi * 16 + l16) * 64 + ko];
            for (int ni = 0; ni < 4; ++ni)
                bf[ni] = *(const bfrag*)&Bs[(wCol + ni * 16 + l16) * 64 + ko];
            for (int mi = 0; mi < 2; ++mi)
                for (int ni = 0; ni < 4; ++ni)
                    acc[mi][ni] = MFMA(af[mi], bf[ni], acc[mi][ni]);
        }
    }

    for (int mi = 0; mi < 2; ++mi)
        for (int ni = 0; ni < 4; ++ni) {
            int gn = n0 + wCol + ni * 16 + l16;
            float bv = bias[gn];
            for (int r = 0; r < 4; ++r) {
                int gm = m0 + wRow + mi * 16 + quad * 4 + r;
                dst[(size_t)gm * D_MODEL + gn] = acc[mi][ni][r] + bv;
            }
        }
}

// ---------------------------------------------------------------------------
// Flash attention (causal), S^T formulation. R6 config (64-row q-blocks,
// 1024 blocks) + XOR-swizzled unpadded LDS (conflict-free staging, <=2-way
// reads) + paired qb map (per-CU work exactly constant: any 4 consecutive
// blocks sum to 66 tiles).
// ---------------------------------------------------------------------------
__global__ __launch_bounds__(256) void k_attn(
    const __bf16* __restrict__ Q, const __bf16* __restrict__ K,
    const __bf16* __restrict__ Vt, __bf16* __restrict__ O)
{
    alignas(16) __shared__ __bf16 Ks[64 * 64];     // 8 KB, swizzled
    alignas(16) __shared__ __bf16 Vts[64 * 64];    // 8 KB, swizzled [d][key]
    alignas(16) __shared__ __bf16 Ps[4][16 * 64];  // 8 KB, swizzled [qrow][key]

    const int tid = threadIdx.x, wid = tid >> 6, lane = tid & 63;
    const int quad = lane >> 4, l16 = lane & 15;
    const int u = (blockIdx.x + blockIdx.y + 16 * blockIdx.z) & 31;
    const int qb = (u & 1) ? 31 - (u >> 1) : (u >> 1);   // paired balance
    const int h = blockIdx.y, b = blockIdx.z;
    const size_t bh = ((size_t)b * NH + h) * SEQ * HD;
    const __bf16* Qg  = Q + bh + (size_t)qb * 64 * HD;
    const __bf16* Kg  = K + bh;
    const __bf16* Vtg = Vt + ((size_t)b * NH + h) * HD * SEQ;  // [d][s]

    bfrag qf[2];
    qf[0] = *(const bfrag*)&Qg[(size_t)(wid * 16 + l16) * HD + quad * 8];
    qf[1] = *(const bfrag*)&Qg[(size_t)(wid * 16 + l16) * HD + 32 + quad * 8];

    const f32x4 zero = {0.f, 0.f, 0.f, 0.f};
    f32x4 o[4];
    for (int dt = 0; dt < 4; ++dt) o[dt] = zero;
    float mrow = NEG_BIG, lrow = 0.f;
    const int q = qb * 64 + wid * 16 + l16;
    const int srcbase = (lane & 48) + quad * 4;
    const int sw = (l16 & 7) * 8;
    const int ntile = qb + 1;

    const int row0 = tid >> 3, seg = (tid & 7) * 8;
    const int sseg = seg ^ ((row0 & 7) * 8);   // swizzled dest k-offset

    uint4 kreg0 = *(const uint4*)&Kg[(size_t)row0 * HD + seg];
    uint4 kreg1 = *(const uint4*)&Kg[(size_t)(row0 + 32) * HD + seg];
    uint4 vreg0 = *(const uint4*)&Vtg[(size_t)row0 * SEQ + seg];
    uint4 vreg1 = *(const uint4*)&Vtg[(size_t)(row0 + 32) * SEQ + seg];

    for (int t = 0; t < ntile; ++t) {
        const int j0 = t * 64;
        __syncthreads();
        *(uint4*)&Ks[row0 * 64 + sseg] = kreg0;
        *(uint4*)&Ks[(row0 + 32) * 64 + sseg] = kreg1;
        *(uint4*)&Vts[row0 * 64 + sseg] = vreg0;
        *(uint4*)&Vts[(row0 + 32) * 64 + sseg] = vreg1;
        if (t + 1 < ntile) {
            const int j1 = j0 + 64;
            kreg0 = *(const uint4*)&Kg[(size_t)(j1 + row0) * HD + seg];
            kreg1 = *(const uint4*)&Kg[(size_t)(j1 + row0 + 32) * HD + seg];
            vreg0 = *(const uint4*)&Vtg[(size_t)row0 * SEQ + j1 + seg];
            vreg1 = *(const uint4*)&Vtg[(size_t)(row0 + 32) * SEQ + j1 + seg];
        }
        __syncthreads();

        f32x4 st[4];
        for (int kt = 0; kt < 4; ++kt) {
            bfrag ka0 = *(const bfrag*)&Ks[(kt * 16 + l16) * 64 + ((quad * 8) ^ sw)];
            bfrag ka1 = *(const bfrag*)&Ks[(kt * 16 + l16) * 64 + ((32 + quad * 8) ^ sw)];
            st[kt] = MFMA(ka1, qf[1], MFMA(ka0, qf[0], zero));
        }

        float mloc = NEG_BIG;
        if (t == ntile - 1) {
            for (int kt = 0; kt < 4; ++kt)
                for (int r = 0; r < 4; ++r) {
                    float v = (j0 + kt * 16 + quad * 4 + r > q) ? NEG_BIG : st[kt][r];
                    st[kt][r] = v;
                    mloc = fmaxf(mloc, v);
                }
        } else {
            for (int kt = 0; kt < 4; ++kt)
                for (int r = 0; r < 4; ++r) mloc = fmaxf(mloc, st[kt][r]);
        }
        float m2 = fmaxf(mloc, __shfl_xor(mloc, 16, 64));
        m2 = fmaxf(m2, __shfl_xor(m2, 32, 64));
        float mnew = fmaxf(mrow, m2);
        float alpha = exp2f(mrow - mnew);
        mrow = mnew;
        float sloc = 0.f;
        for (int kt = 0; kt < 4; ++kt)
            for (int r = 0; r < 4; ++r) {
                float p = exp2f(st[kt][r] - mnew);
                st[kt][r] = p;
                sloc += p;
            }

        // P^T writes (swizzled): keys kt*16+quad*4 .. +3 per b64
        for (int kt = 0; kt < 4; ++kt) {
            union { unsigned long long u; __bf16 h4[4]; } pk;
            for (int r = 0; r < 4; ++r) pk.h4[r] = (__bf16)st[kt][r];
            *(unsigned long long*)&Ps[wid][l16 * 64 + ((kt * 16 + quad * 4) ^ sw)] = pk.u;
        }

        for (int r = 0; r < 4; ++r) {
            float ar = __shfl(alpha, srcbase + r, 64);
            for (int dt = 0; dt < 4; ++dt) o[dt][r] *= ar;
        }
        asm volatile("s_waitcnt lgkmcnt(0)" ::: "memory");

        for (int c = 0; c < 2; ++c) {
            int ko = (c * 32 + quad * 8) ^ sw;
            bfrag pf = *(const bfrag*)&Ps[wid][l16 * 64 + ko];
            for (int dt = 0; dt < 4; ++dt) {
                bfrag vf = *(const bfrag*)&Vts[(dt * 16 + l16) * 64 + ko];
                o[dt] = MFMA(pf, vf, o[dt]);
            }
        }

        float s2 = sloc + __shfl_xor(sloc, 16, 64);
        s2 = s2 + __shfl_xor(s2, 32, 64);
        lrow = alpha * lrow + s2;
    }

    for (int r = 0; r < 4; ++r) {
        float lr = __shfl(lrow, srcbase + r, 64);
        float inv = 1.0f / lr;
        size_t base = ((size_t)b * SEQ + qb * 64 + wid * 16 + quad * 4 + r) * D_MODEL
                    + (size_t)h * HD;
        for (int dt = 0; dt < 4; ++dt)
            O[base + dt * 16 + l16] = (__bf16)(o[dt][r] * inv);
    }
}

// ---------------------------------------------------------------------------
extern "C" void kernel_launch(void* const* d_in, const int* in_sizes, int n_in,
                              void* d_out, int out_size, void* d_ws, size_t ws_size,
                              hipStream_t stream)
{
    const float* x  = (const float*)d_in[0];
    const float* Wq = (const float*)d_in[1];
    const float* bq = (const float*)d_in[2];
    const float* Wk = (const float*)d_in[3];
    const float* bk = (const float*)d_in[4];
    const float* Wv = (const float*)d_in[5];
    const float* bv = (const float*)d_in[6];
    const float* Wo = (const float*)d_in[7];
    const float* bo = (const float*)d_in[8];

    __bf16* ws = (__bf16*)d_ws;
    const size_t M1 = 1024u * 1024u;
    __bf16* qkv    = ws;                      // Q @0, K @4M, Vt @8M (24 MB)
    __bf16* attn_o = ws + 12 * M1;            // 4M (8 MB)
    __bf16* Wt     = ws + 16 * M1;            // 4M (8 MB)
    __bf16* xb     = ws + 20 * M1;            // 4M (8 MB) -> 48 MB total

    const bool fast = ws_size >= (size_t)48 * 1024 * 1024;

    if (fast) {
        k_prep<<<dim3(16, 16, 5), 256, 0, stream>>>(x, Wq, Wk, Wv, Wo, Wt, xb);
        k_gemm128<0, true><<<dim3(8, 32, 3), 256, 0, stream>>>(
            xb, Wt, Wt + M1, Wt + 2 * M1, bq, bk, bv, qkv);
        k_attn<<<dim3(32, 16, 2), 256, 0, stream>>>(
            qkv, qkv + 4 * M1, qkv + 8 * M1, attn_o);
        k_gemm_out<<<dim3(8, 64), 256, 0, stream>>>(
            attn_o, Wt + 3 * M1, bo, (float*)d_out);
    } else {
        k_gemm128<0, false><<<dim3(8, 32, 3), 256, 0, stream>>>(
            x, Wq, Wk, Wv, bq, bk, bv, qkv);
        k_attn<<<dim3(32, 16, 2), 256, 0, stream>>>(
            qkv, qkv + 4 * M1, qkv + 8 * M1, attn_o);
        k_gemm128<1, false><<<dim3(8, 32, 1), 256, 0, stream>>>(
            attn_o, Wo, Wo, Wo, bo, bo, bo, (float*)d_out);
    }
}